// Round 1
// baseline (3261.619 us; speedup 1.0000x reference)
//
#include <hip/hip_runtime.h>
#include <math.h>

#define B 4
#define T 4096
#define C 1024
#define HS 64

// ---------------------------------------------------------------------------
// Kernel A: fused Q/K/V projection.
// One 64-thread block per (b,t) row. Stage x-row in LDS; lane h walks c,
// reading W[c*HS+h] (coalesced 256B across the wave per c).
// ---------------------------------------------------------------------------
__global__ __launch_bounds__(64) void qkv_proj_kernel(
    const float* __restrict__ x,
    const float* __restrict__ Wq, const float* __restrict__ bq,
    const float* __restrict__ Wk, const float* __restrict__ bk,
    const float* __restrict__ Wv, const float* __restrict__ bv,
    float* __restrict__ Q, float* __restrict__ K, float* __restrict__ V) {
  const int row = blockIdx.x;       // 0 .. B*T-1
  const int h   = threadIdx.x;      // 0 .. 63
  __shared__ float xs[C];
  const float* xr = x + (size_t)row * C;
#pragma unroll
  for (int i = 0; i < C / 64; ++i) xs[h + i * 64] = xr[h + i * 64];
  __syncthreads();

  float aq = bq[h], ak = bk[h], av = bv[h];
  for (int c = 0; c < C; ++c) {
    const float xc = xs[c];                 // broadcast read (no conflict)
    aq = fmaf(xc, Wq[c * HS + h], aq);
    ak = fmaf(xc, Wk[c * HS + h], ak);
    av = fmaf(xc, Wv[c * HS + h], av);
  }
  const size_t o = (size_t)row * HS + h;
  Q[o] = aq; K[o] = ak; V[o] = av;
}

// ---------------------------------------------------------------------------
// Kernel B: causal attention, one wave per query row, lane = head dim.
// Online softmax (running m, s); score via 6-step __shfl_xor wave reduce.
// ---------------------------------------------------------------------------
__global__ __launch_bounds__(64) void attn_kernel(
    const float* __restrict__ Q, const float* __restrict__ K,
    const float* __restrict__ V, float* __restrict__ out) {
  const int idx = blockIdx.x;       // 0 .. B*T-1
  const int b   = idx / T;
  const int qi  = idx % T;
  const int l   = threadIdx.x;      // head dim lane

  const float scale = 0.03125f;     // C^-0.5 = 1/32
  const float* Kb = K + (size_t)b * T * HS;
  const float* Vb = V + (size_t)b * T * HS;

  const float ql = Q[((size_t)b * T + qi) * HS + l] * scale;

  float m = -INFINITY;
  float s = 0.0f;
  float o = 0.0f;

  for (int j = 0; j <= qi; ++j) {
    const float kl = Kb[(size_t)j * HS + l];
    const float vl = Vb[(size_t)j * HS + l];
    float p = ql * kl;
#pragma unroll
    for (int off = 32; off; off >>= 1) p += __shfl_xor(p, off, 64);
    const float score = p;                 // full dot, all lanes
    const float nm    = fmaxf(m, score);
    const float corr  = __expf(m - nm);    // first iter: exp(-inf)=0
    const float pe    = __expf(score - nm);
    s = s * corr + pe;
    o = o * corr + pe * vl;
    m = nm;
  }
  out[((size_t)b * T + qi) * HS + l] = o / s;
}

extern "C" void kernel_launch(void* const* d_in, const int* in_sizes, int n_in,
                              void* d_out, int out_size, void* d_ws, size_t ws_size,
                              hipStream_t stream) {
  const float* x  = (const float*)d_in[0];
  const float* Wq = (const float*)d_in[1];
  const float* bq = (const float*)d_in[2];
  const float* Wk = (const float*)d_in[3];
  const float* bk = (const float*)d_in[4];
  const float* Wv = (const float*)d_in[5];
  const float* bv = (const float*)d_in[6];
  float* out = (float*)d_out;

  float* Q = (float*)d_ws;
  float* K = Q + (size_t)B * T * HS;
  float* V = K + (size_t)B * T * HS;

  qkv_proj_kernel<<<B * T, 64, 0, stream>>>(x, Wq, bq, Wk, bk, Wv, bv, Q, K, V);
  attn_kernel<<<B * T, 64, 0, stream>>>(Q, K, V, out);
}

// Round 2
// 468.492 us; speedup vs baseline: 6.9619x; 6.9619x over previous
//
#include <hip/hip_runtime.h>
#include <math.h>

#define B 4
#define T 4096
#define C 1024
#define HS 64

typedef __attribute__((ext_vector_type(8))) short short8;
typedef __attribute__((ext_vector_type(4))) short short4v;
typedef __attribute__((ext_vector_type(4))) float f32x4;

#define MFMA16(a, b, c) __builtin_amdgcn_mfma_f32_16x16x32_bf16((a), (b), (c), 0, 0, 0)

static __device__ __forceinline__ unsigned short f2bf(float f) {
  union { float f; unsigned u; } v; v.f = f;
  unsigned r = v.u + 0x7FFFu + ((v.u >> 16) & 1u);  // RNE to bf16
  return (unsigned short)(r >> 16);
}

// ---------------------------------------------------------------------------
// Kernel A: fused Q/K/V projection (fp32 math), emitting:
//   Qb [B*T][64] bf16, pre-scaled by C^-0.5 = 1/32
//   Kb [B*T][64] bf16
//   Vt [B][64][T] bf16 (transposed V, so PV B-fragments are contiguous)
// ---------------------------------------------------------------------------
__global__ __launch_bounds__(64) void qkv_proj_kernel(
    const float* __restrict__ x,
    const float* __restrict__ Wq, const float* __restrict__ bq,
    const float* __restrict__ Wk, const float* __restrict__ bk,
    const float* __restrict__ Wv, const float* __restrict__ bv,
    unsigned short* __restrict__ Qb, unsigned short* __restrict__ Kb,
    unsigned short* __restrict__ Vt) {
  const int row = blockIdx.x;       // 0 .. B*T-1
  const int h   = threadIdx.x;      // 0 .. 63
  __shared__ float xs[C];
  const float* xr = x + (size_t)row * C;
#pragma unroll
  for (int i = 0; i < C / 64; ++i) xs[h + i * 64] = xr[h + i * 64];
  __syncthreads();

  float aq = bq[h], ak = bk[h], av = bv[h];
  for (int c = 0; c < C; ++c) {
    const float xc = xs[c];
    aq = fmaf(xc, Wq[c * HS + h], aq);
    ak = fmaf(xc, Wk[c * HS + h], ak);
    av = fmaf(xc, Wv[c * HS + h], av);
  }
  const int b = row >> 12;          // T = 4096
  const int t = row & (T - 1);
  const size_t o = (size_t)row * HS + h;
  Qb[o] = f2bf(aq * 0.03125f);
  Kb[o] = f2bf(ak);
  Vt[((size_t)b * HS + h) * T + t] = f2bf(av);
}

// ---------------------------------------------------------------------------
// Kernel B: MFMA flash attention.
// 4 waves/block, 16 q-rows per wave, KV-blocks of 32 keys.
// Swapped QK^T: S^T = mfma(K_frag, Q_frag) so softmax reduce is reg-local +
// shfl_xor(16,32). P round-trips through padded per-wave LDS to become the
// PV A-fragment. Double-buffered K/V fragment prefetch.
//
// Fragment layouts (16x16x32 bf16):
//   A: lane holds A[l%16][8*(l/16)+e], e=0..7 (contiguous 16B)
//   B: lane holds B[8*(l/16)+e][l%16]
//   C/D: lane holds D[4*(l/16)+r][l%16], r=0..3   [HW-verified]
// ---------------------------------------------------------------------------
__global__ __launch_bounds__(256) void attn_kernel(
    const unsigned short* __restrict__ Qb,
    const unsigned short* __restrict__ Kb,
    const unsigned short* __restrict__ Vt,
    float* __restrict__ out) {
  const int lane = threadIdx.x & 63;
  const int wid  = threadIdx.x >> 6;   // 0..3
  const int col  = lane & 15;
  const int grp  = lane >> 4;          // 0..3
  const int bidx = blockIdx.x;
  const int b    = bidx >> 6;          // 64 q-tiles per batch
  const int qt   = bidx & 63;
  const int qbase = qt * 64 + wid * 16;
  const int qg = qbase + col;          // this lane's q row (for S^T columns)

  __shared__ alignas(16) unsigned short plds[4][16][40];  // padded: 80B rows

  const unsigned short* Qrow = Qb + (size_t)(b * T + qbase) * HS;
  const unsigned short* Kbb  = Kb + (size_t)b * T * HS;
  const unsigned short* Vtb  = Vt + (size_t)b * HS * T;

  // Q fragments (B-operand): lane holds Q[qbase+col][8*grp+e (+32)]
  const short8 qf0 = *(const short8*)(Qrow + col * HS + grp * 8);
  const short8 qf1 = *(const short8*)(Qrow + col * HS + grp * 8 + 32);

  f32x4 acc[4];
#pragma unroll
  for (int nt = 0; nt < 4; ++nt) acc[nt] = (f32x4){0.f, 0.f, 0.f, 0.f};
  float m = -INFINITY, lsum = 0.f;

  const int nkv = (qbase + 16 + 31) >> 5;  // KV blocks needed for qmax=qbase+15

  short8 kfA[4], vfA[4], kfB[4], vfB[4];

  auto loadKV = [&](int k0, short8 (&kd)[4], short8 (&vd)[4]) {
    const unsigned short* Kp = Kbb + (size_t)(k0 + col) * HS + grp * 8;
    kd[0] = *(const short8*)(Kp);
    kd[1] = *(const short8*)(Kp + 32);
    kd[2] = *(const short8*)(Kp + 16 * HS);
    kd[3] = *(const short8*)(Kp + 16 * HS + 32);
    const unsigned short* Vp = Vtb + (size_t)col * T + k0 + grp * 8;
    vd[0] = *(const short8*)(Vp);
    vd[1] = *(const short8*)(Vp + 16 * T);
    vd[2] = *(const short8*)(Vp + 32 * T);
    vd[3] = *(const short8*)(Vp + 48 * T);
  };

  auto step = [&](int kb, short8 (&kc)[4], short8 (&vc)[4],
                  short8 (&kn)[4], short8 (&vn)[4]) {
    const int k0 = kb * 32;
    // prefetch next KV block (clamped in-bounds; unused on last iter)
    int kp = k0 + 32;
    kp = (kp <= T - 32) ? kp : (T - 32);
    loadKV(kp, kn, vn);

    // ---- QK^T: S^T tiles (keys x q). scale already folded into Q. ----
    f32x4 s0 = (f32x4){0.f, 0.f, 0.f, 0.f};
    f32x4 s1 = (f32x4){0.f, 0.f, 0.f, 0.f};
    s0 = MFMA16(kc[0], qf0, s0);
    s0 = MFMA16(kc[1], qf1, s0);
    s1 = MFMA16(kc[2], qf0, s1);
    s1 = MFMA16(kc[3], qf1, s1);

    // ---- causal mask + online softmax (q = col; keys across regs/groups) ----
    float pe[8];
    float pm = -INFINITY;
#pragma unroll
    for (int r = 0; r < 4; ++r) {
      const int key0 = k0 + 4 * grp + r;
      const float v0 = (key0 <= qg) ? s0[r] : -INFINITY;
      const float v1 = (key0 + 16 <= qg) ? s1[r] : -INFINITY;
      pe[r] = v0;
      pe[4 + r] = v1;
      pm = fmaxf(pm, fmaxf(v0, v1));
    }
    pm = fmaxf(pm, __shfl_xor(pm, 16, 64));
    pm = fmaxf(pm, __shfl_xor(pm, 32, 64));
    const float mn = fmaxf(m, pm);
    const float corr = __expf(m - mn);
    float ps = 0.f;
#pragma unroll
    for (int i = 0; i < 8; ++i) {
      pe[i] = __expf(pe[i] - mn);   // exp(-inf - finite) = 0 handles mask
      ps += pe[i];
    }
    ps += __shfl_xor(ps, 16, 64);
    ps += __shfl_xor(ps, 32, 64);
    lsum = lsum * corr + ps;
    m = mn;

    // ---- P -> LDS (bf16) to re-layout into PV A-fragment ----
    short4v w0, w1;
#pragma unroll
    for (int r = 0; r < 4; ++r) {
      w0[r] = (short)f2bf(pe[r]);
      w1[r] = (short)f2bf(pe[4 + r]);
    }
    *(short4v*)(&plds[wid][col][4 * grp]) = w0;        // keys 4g..4g+3
    *(short4v*)(&plds[wid][col][16 + 4 * grp]) = w1;   // keys 16+4g..
    const short8 pa = *(const short8*)(&plds[wid][col][8 * grp]);

    // ---- rescale accumulator (corr per output q-row = 4*grp + r) ----
    float cr[4];
#pragma unroll
    for (int r = 0; r < 4; ++r) cr[r] = __shfl(corr, 4 * grp + r, 64);
#pragma unroll
    for (int nt = 0; nt < 4; ++nt) {
#pragma unroll
      for (int r = 0; r < 4; ++r) acc[nt][r] *= cr[r];
    }

    // ---- PV: out[q][d] += P[q][k] V[k][d] ----
#pragma unroll
    for (int nt = 0; nt < 4; ++nt) acc[nt] = MFMA16(pa, vc[nt], acc[nt]);
  };

  loadKV(0, kfA, vfA);
  int kb = 0;
  for (; kb + 2 <= nkv; kb += 2) {
    step(kb,     kfA, vfA, kfB, vfB);
    step(kb + 1, kfB, vfB, kfA, vfA);
  }
  if (kb < nkv) step(kb, kfA, vfA, kfB, vfB);

  // ---- epilogue: divide by softmax denom, write fp32 ----
  float lr[4];
#pragma unroll
  for (int r = 0; r < 4; ++r) lr[r] = __shfl(lsum, 4 * grp + r, 64);
  float* op = out + (size_t)(b * T + qbase) * HS;
#pragma unroll
  for (int nt = 0; nt < 4; ++nt) {
#pragma unroll
    for (int r = 0; r < 4; ++r) {
      op[(size_t)(4 * grp + r) * HS + col + 16 * nt] = acc[nt][r] / lr[r];
    }
  }
}

extern "C" void kernel_launch(void* const* d_in, const int* in_sizes, int n_in,
                              void* d_out, int out_size, void* d_ws, size_t ws_size,
                              hipStream_t stream) {
  const float* x  = (const float*)d_in[0];
  const float* Wq = (const float*)d_in[1];
  const float* bq = (const float*)d_in[2];
  const float* Wk = (const float*)d_in[3];
  const float* bk = (const float*)d_in[4];
  const float* Wv = (const float*)d_in[5];
  const float* bv = (const float*)d_in[6];
  float* out = (float*)d_out;

  unsigned short* Qb = (unsigned short*)d_ws;
  unsigned short* Kb = Qb + (size_t)B * T * HS;
  unsigned short* Vt = Kb + (size_t)B * T * HS;

  qkv_proj_kernel<<<B * T, 64, 0, stream>>>(x, Wq, bq, Wk, bk, Wv, bv, Qb, Kb, Vt);
  attn_kernel<<<B * (T / 64), 256, 0, stream>>>(Qb, Kb, Vt, out);
}

// Round 3
// 169.758 us; speedup vs baseline: 19.2133x; 2.7598x over previous
//
#include <hip/hip_runtime.h>
#include <math.h>

#define B 4
#define T 4096
#define C 1024
#define HS 64

typedef __attribute__((ext_vector_type(8))) short short8;
typedef __attribute__((ext_vector_type(4))) short short4v;
typedef __attribute__((ext_vector_type(4))) float f32x4;

#define MFMA16(a, b, c) __builtin_amdgcn_mfma_f32_16x16x32_bf16((a), (b), (c), 0, 0, 0)

static __device__ __forceinline__ unsigned short f2bf(float f) {
  union { float f; unsigned u; } v; v.f = f;
  unsigned r = v.u + 0x7FFFu + ((v.u >> 16) & 1u);  // RNE to bf16
  return (unsigned short)(r >> 16);
}

// ---------------------------------------------------------------------------
// Kernel 0: convert W to bf16, transposed: Wt[n][c], n = q(0-63)|k(64-127)|v(128-191).
// Gives contiguous 16B B-fragment loads in the proj GEMM. 384KB, L2-resident.
// ---------------------------------------------------------------------------
__global__ __launch_bounds__(64) void conv_w_kernel(
    const float* __restrict__ Wq, const float* __restrict__ Wk,
    const float* __restrict__ Wv, unsigned short* __restrict__ Wt) {
  const int n = blockIdx.x;              // 0..191
  const float* W = (n < 64) ? Wq : (n < 128) ? Wk : Wv;
  const int h = n & 63;
  for (int c = threadIdx.x; c < C; c += 64)
    Wt[(size_t)n * C + c] = f2bf(W[(size_t)c * HS + h]);
}

// ---------------------------------------------------------------------------
// Kernel 1: fused QKV projection as MFMA GEMM.
// 512 blocks x 1 wave; wave = 32 x-rows (2 M-tiles) x 192 out-cols (12 N-tiles).
// A: x fp32 direct from global (compulsory traffic), cvt->bf16 in-reg,
//    double-buffered with NAMED buffers (static indices).
// B: contiguous short8 from Wt (L1/L2 resident, 12KB working set per K-step).
// Epilogue: +bias, Q pre-scaled by C^-0.5, writes Qb/Kb/Vt (attn's layouts).
// ---------------------------------------------------------------------------
__global__ __launch_bounds__(64) void proj_kernel(
    const float* __restrict__ x, const unsigned short* __restrict__ Wt,
    const float* __restrict__ bq, const float* __restrict__ bk,
    const float* __restrict__ bv,
    unsigned short* __restrict__ Qb, unsigned short* __restrict__ Kb,
    unsigned short* __restrict__ Vt) {
  const int m0   = blockIdx.x * 32;
  const int lane = threadIdx.x;
  const int col  = lane & 15, grp = lane >> 4;

  const float* xr0 = x + (size_t)(m0 + col) * C + grp * 8;
  const float* xr1 = xr0 + (size_t)16 * C;

  f32x4 acc0[12], acc1[12];
#pragma unroll
  for (int nt = 0; nt < 12; ++nt) {
    acc0[nt] = (f32x4){0.f, 0.f, 0.f, 0.f};
    acc1[nt] = (f32x4){0.f, 0.f, 0.f, 0.f};
  }

  auto loadA = [&](int kc, short8& a0, short8& a1) {
    const f32x4 p0 = *(const f32x4*)(xr0 + kc);
    const f32x4 p1 = *(const f32x4*)(xr0 + kc + 4);
    const f32x4 q0 = *(const f32x4*)(xr1 + kc);
    const f32x4 q1 = *(const f32x4*)(xr1 + kc + 4);
    short8 a, b;
#pragma unroll
    for (int e = 0; e < 4; ++e) {
      a[e] = (short)f2bf(p0[e]); a[4 + e] = (short)f2bf(p1[e]);
      b[e] = (short)f2bf(q0[e]); b[4 + e] = (short)f2bf(q1[e]);
    }
    a0 = a; a1 = b;
  };

  auto stepK = [&](int kc, short8 a0, short8 a1) {
    const unsigned short* wp = Wt + (size_t)col * C + kc + grp * 8;
#pragma unroll
    for (int nt = 0; nt < 12; ++nt) {
      const short8 bf = *(const short8*)(wp + (size_t)nt * 16 * C);
      acc0[nt] = MFMA16(a0, bf, acc0[nt]);
      acc1[nt] = MFMA16(a1, bf, acc1[nt]);
    }
  };

  short8 aA0, aA1, aB0, aB1;
  loadA(0, aA0, aA1);
  for (int kc = 0; kc < C; kc += 64) {
    loadA(kc + 32, aB0, aB1);            // kc+32 <= 992, always valid
    stepK(kc, aA0, aA1);
    if (kc + 64 < C) loadA(kc + 64, aA0, aA1);
    stepK(kc + 32, aB0, aB1);
  }

  // ---- epilogue: bias, scale, write out in attn's layouts ----
  auto writeOut = [&](int row, int n, float v) {
    if (n < 64)       Qb[(size_t)row * HS + n] = f2bf(v * 0.03125f);
    else if (n < 128) Kb[(size_t)row * HS + (n - 64)] = f2bf(v);
    else Vt[((size_t)(row >> 12) * HS + (n - 128)) * T + (row & (T - 1))] = f2bf(v);
  };
#pragma unroll
  for (int nt = 0; nt < 12; ++nt) {
    const int n = nt * 16 + col;
    const float bias = (n < 64) ? bq[n] : (n < 128) ? bk[n - 64] : bv[n - 128];
#pragma unroll
    for (int r = 0; r < 4; ++r) {
      const int row0 = m0 + 4 * grp + r;
      writeOut(row0,      n, acc0[nt][r] + bias);
      writeOut(row0 + 16, n, acc1[nt][r] + bias);
    }
  }
}

// ---------------------------------------------------------------------------
// Kernel 2: MFMA flash attention (unchanged from round 2 — verified).
// ---------------------------------------------------------------------------
__global__ __launch_bounds__(256) void attn_kernel(
    const unsigned short* __restrict__ Qb,
    const unsigned short* __restrict__ Kb,
    const unsigned short* __restrict__ Vt,
    float* __restrict__ out) {
  const int lane = threadIdx.x & 63;
  const int wid  = threadIdx.x >> 6;   // 0..3
  const int col  = lane & 15;
  const int grp  = lane >> 4;          // 0..3
  const int bidx = blockIdx.x;
  const int b    = bidx >> 6;          // 64 q-tiles per batch
  const int qt   = bidx & 63;
  const int qbase = qt * 64 + wid * 16;
  const int qg = qbase + col;          // this lane's q row (for S^T columns)

  __shared__ alignas(16) unsigned short plds[4][16][40];  // padded: 80B rows

  const unsigned short* Qrow = Qb + (size_t)(b * T + qbase) * HS;
  const unsigned short* Kbb  = Kb + (size_t)b * T * HS;
  const unsigned short* Vtb  = Vt + (size_t)b * HS * T;

  const short8 qf0 = *(const short8*)(Qrow + col * HS + grp * 8);
  const short8 qf1 = *(const short8*)(Qrow + col * HS + grp * 8 + 32);

  f32x4 acc[4];
#pragma unroll
  for (int nt = 0; nt < 4; ++nt) acc[nt] = (f32x4){0.f, 0.f, 0.f, 0.f};
  float m = -INFINITY, lsum = 0.f;

  const int nkv = (qbase + 16 + 31) >> 5;

  short8 kfA[4], vfA[4], kfB[4], vfB[4];

  auto loadKV = [&](int k0, short8 (&kd)[4], short8 (&vd)[4]) {
    const unsigned short* Kp = Kbb + (size_t)(k0 + col) * HS + grp * 8;
    kd[0] = *(const short8*)(Kp);
    kd[1] = *(const short8*)(Kp + 32);
    kd[2] = *(const short8*)(Kp + 16 * HS);
    kd[3] = *(const short8*)(Kp + 16 * HS + 32);
    const unsigned short* Vp = Vtb + (size_t)col * T + k0 + grp * 8;
    vd[0] = *(const short8*)(Vp);
    vd[1] = *(const short8*)(Vp + 16 * T);
    vd[2] = *(const short8*)(Vp + 32 * T);
    vd[3] = *(const short8*)(Vp + 48 * T);
  };

  auto step = [&](int kb, short8 (&kc)[4], short8 (&vc)[4],
                  short8 (&kn)[4], short8 (&vn)[4]) {
    const int k0 = kb * 32;
    int kp = k0 + 32;
    kp = (kp <= T - 32) ? kp : (T - 32);
    loadKV(kp, kn, vn);

    f32x4 s0 = (f32x4){0.f, 0.f, 0.f, 0.f};
    f32x4 s1 = (f32x4){0.f, 0.f, 0.f, 0.f};
    s0 = MFMA16(kc[0], qf0, s0);
    s0 = MFMA16(kc[1], qf1, s0);
    s1 = MFMA16(kc[2], qf0, s1);
    s1 = MFMA16(kc[3], qf1, s1);

    float pe[8];
    float pm = -INFINITY;
#pragma unroll
    for (int r = 0; r < 4; ++r) {
      const int key0 = k0 + 4 * grp + r;
      const float v0 = (key0 <= qg) ? s0[r] : -INFINITY;
      const float v1 = (key0 + 16 <= qg) ? s1[r] : -INFINITY;
      pe[r] = v0;
      pe[4 + r] = v1;
      pm = fmaxf(pm, fmaxf(v0, v1));
    }
    pm = fmaxf(pm, __shfl_xor(pm, 16, 64));
    pm = fmaxf(pm, __shfl_xor(pm, 32, 64));
    const float mn = fmaxf(m, pm);
    const float corr = __expf(m - mn);
    float ps = 0.f;
#pragma unroll
    for (int i = 0; i < 8; ++i) {
      pe[i] = __expf(pe[i] - mn);
      ps += pe[i];
    }
    ps += __shfl_xor(ps, 16, 64);
    ps += __shfl_xor(ps, 32, 64);
    lsum = lsum * corr + ps;
    m = mn;

    short4v w0, w1;
#pragma unroll
    for (int r = 0; r < 4; ++r) {
      w0[r] = (short)f2bf(pe[r]);
      w1[r] = (short)f2bf(pe[4 + r]);
    }
    *(short4v*)(&plds[wid][col][4 * grp]) = w0;
    *(short4v*)(&plds[wid][col][16 + 4 * grp]) = w1;
    const short8 pa = *(const short8*)(&plds[wid][col][8 * grp]);

    float cr[4];
#pragma unroll
    for (int r = 0; r < 4; ++r) cr[r] = __shfl(corr, 4 * grp + r, 64);
#pragma unroll
    for (int nt = 0; nt < 4; ++nt) {
#pragma unroll
      for (int r = 0; r < 4; ++r) acc[nt][r] *= cr[r];
    }

#pragma unroll
    for (int nt = 0; nt < 4; ++nt) acc[nt] = MFMA16(pa, vc[nt], acc[nt]);
  };

  loadKV(0, kfA, vfA);
  int kb = 0;
  for (; kb + 2 <= nkv; kb += 2) {
    step(kb,     kfA, vfA, kfB, vfB);
    step(kb + 1, kfB, vfB, kfA, vfA);
  }
  if (kb < nkv) step(kb, kfA, vfA, kfB, vfB);

  float lr[4];
#pragma unroll
  for (int r = 0; r < 4; ++r) lr[r] = __shfl(lsum, 4 * grp + r, 64);
  float* op = out + (size_t)(b * T + qbase) * HS;
#pragma unroll
  for (int nt = 0; nt < 4; ++nt) {
#pragma unroll
    for (int r = 0; r < 4; ++r) {
      op[(size_t)(4 * grp + r) * HS + col + 16 * nt] = acc[nt][r] / lr[r];
    }
  }
}

extern "C" void kernel_launch(void* const* d_in, const int* in_sizes, int n_in,
                              void* d_out, int out_size, void* d_ws, size_t ws_size,
                              hipStream_t stream) {
  const float* x  = (const float*)d_in[0];
  const float* Wq = (const float*)d_in[1];
  const float* bq = (const float*)d_in[2];
  const float* Wk = (const float*)d_in[3];
  const float* bk = (const float*)d_in[4];
  const float* Wv = (const float*)d_in[5];
  const float* bv = (const float*)d_in[6];
  float* out = (float*)d_out;

  unsigned short* Qb = (unsigned short*)d_ws;
  unsigned short* Kb = Qb + (size_t)B * T * HS;
  unsigned short* Vt = Kb + (size_t)B * T * HS;
  unsigned short* Wt = Vt + (size_t)B * T * HS;

  conv_w_kernel<<<192, 64, 0, stream>>>(Wq, Wk, Wv, Wt);
  proj_kernel<<<B * T / 32, 64, 0, stream>>>(x, Wt, bq, bk, bv, Qb, Kb, Vt);
  attn_kernel<<<B * (T / 64), 256, 0, stream>>>(Qb, Kb, Vt, out);
}

// Round 4
// 155.242 us; speedup vs baseline: 21.0099x; 1.0935x over previous
//
#include <hip/hip_runtime.h>
#include <math.h>

#define B 4
#define T 4096
#define C 1024
#define HS 64

typedef __attribute__((ext_vector_type(8))) short short8;
typedef __attribute__((ext_vector_type(4))) short short4v;
typedef __attribute__((ext_vector_type(4))) float f32x4;

#define MFMA16(a, b, c) __builtin_amdgcn_mfma_f32_16x16x32_bf16((a), (b), (c), 0, 0, 0)

static __device__ __forceinline__ unsigned short f2bf(float f) {
  union { float f; unsigned u; } v; v.f = f;
  unsigned r = v.u + 0x7FFFu + ((v.u >> 16) & 1u);  // RNE to bf16
  return (unsigned short)(r >> 16);
}

// ---------------------------------------------------------------------------
// Kernel 0: W -> bf16 transposed Wt[n][c], n = q|k|v. 384KB, L2-resident.
// ---------------------------------------------------------------------------
__global__ __launch_bounds__(64) void conv_w_kernel(
    const float* __restrict__ Wq, const float* __restrict__ Wk,
    const float* __restrict__ Wv, unsigned short* __restrict__ Wt) {
  const int n = blockIdx.x;              // 0..191
  const float* W = (n < 64) ? Wq : (n < 128) ? Wk : Wv;
  const int h = n & 63;
  for (int c = threadIdx.x; c < C; c += 64)
    Wt[(size_t)n * C + c] = f2bf(W[(size_t)c * HS + h]);
}

// ---------------------------------------------------------------------------
// Kernel 1: fused QKV projection GEMM. 512 blocks x 1 wave; wave = 32 rows x
// 192 cols. 2-deep A prefetch (4 named buffers) to keep ~8KB/wave in flight.
// ---------------------------------------------------------------------------
__global__ __launch_bounds__(64) void proj_kernel(
    const float* __restrict__ x, const unsigned short* __restrict__ Wt,
    const float* __restrict__ bq, const float* __restrict__ bk,
    const float* __restrict__ bv,
    unsigned short* __restrict__ Qb, unsigned short* __restrict__ Kb,
    unsigned short* __restrict__ Vt) {
  const int m0   = blockIdx.x * 32;
  const int lane = threadIdx.x;
  const int col  = lane & 15, grp = lane >> 4;

  const float* xr0 = x + (size_t)(m0 + col) * C + grp * 8;
  const float* xr1 = xr0 + (size_t)16 * C;

  f32x4 acc0[12], acc1[12];
#pragma unroll
  for (int nt = 0; nt < 12; ++nt) {
    acc0[nt] = (f32x4){0.f, 0.f, 0.f, 0.f};
    acc1[nt] = (f32x4){0.f, 0.f, 0.f, 0.f};
  }

  auto loadA = [&](int kc, short8& a0, short8& a1) {
    const f32x4 p0 = *(const f32x4*)(xr0 + kc);
    const f32x4 p1 = *(const f32x4*)(xr0 + kc + 4);
    const f32x4 q0 = *(const f32x4*)(xr1 + kc);
    const f32x4 q1 = *(const f32x4*)(xr1 + kc + 4);
    short8 a, b;
#pragma unroll
    for (int e = 0; e < 4; ++e) {
      a[e] = (short)f2bf(p0[e]); a[4 + e] = (short)f2bf(p1[e]);
      b[e] = (short)f2bf(q0[e]); b[4 + e] = (short)f2bf(q1[e]);
    }
    a0 = a; a1 = b;
  };

  auto stepK = [&](int kc, short8 a0, short8 a1) {
    const unsigned short* wp = Wt + (size_t)col * C + kc + grp * 8;
#pragma unroll
    for (int nt = 0; nt < 12; ++nt) {
      const short8 bf = *(const short8*)(wp + (size_t)nt * 16 * C);
      acc0[nt] = MFMA16(a0, bf, acc0[nt]);
      acc1[nt] = MFMA16(a1, bf, acc1[nt]);
    }
  };

  short8 aA0, aA1, aB0, aB1, aC0, aC1, aD0, aD1;
  loadA(0, aA0, aA1);
  loadA(32, aB0, aB1);
  for (int kc = 0; kc < C; kc += 128) {
    loadA(kc + 64, aC0, aC1);                       // max 960: in range
    stepK(kc, aA0, aA1);
    loadA(kc + 96, aD0, aD1);                       // max 992: in range
    stepK(kc + 32, aB0, aB1);
    int k1 = kc + 128; if (k1 > C - 32) k1 = C - 32;  // tail: harmless dup
    loadA(k1, aA0, aA1);
    stepK(kc + 64, aC0, aC1);
    int k2 = kc + 160; if (k2 > C - 32) k2 = C - 32;
    loadA(k2, aB0, aB1);
    stepK(kc + 96, aD0, aD1);
  }

  auto writeOut = [&](int row, int n, float v) {
    if (n < 64)       Qb[(size_t)row * HS + n] = f2bf(v * 0.03125f);
    else if (n < 128) Kb[(size_t)row * HS + (n - 64)] = f2bf(v);
    else Vt[((size_t)(row >> 12) * HS + (n - 128)) * T + (row & (T - 1))] = f2bf(v);
  };
#pragma unroll
  for (int nt = 0; nt < 12; ++nt) {
    const int n = nt * 16 + col;
    const float bias = (n < 64) ? bq[n] : (n < 128) ? bk[n - 64] : bv[n - 128];
#pragma unroll
    for (int r = 0; r < 4; ++r) {
      const int row0 = m0 + 4 * grp + r;
      writeOut(row0,      n, acc0[nt][r] + bias);
      writeOut(row0 + 16, n, acc1[nt][r] + bias);
    }
  }
}

// ---------------------------------------------------------------------------
// Kernel 2: MFMA flash attention, KV-split across waves.
// 1024 blocks (one per 16-row q-tile) x 4 waves; wave w takes KV blocks
// w, w+4, w+8, ... with private (m, l, acc); LDS merge at the end.
// ---------------------------------------------------------------------------
__global__ __launch_bounds__(256) void attn_kernel(
    const unsigned short* __restrict__ Qb,
    const unsigned short* __restrict__ Kb,
    const unsigned short* __restrict__ Vt,
    float* __restrict__ out) {
  const int lane = threadIdx.x & 63;
  const int w    = threadIdx.x >> 6;   // 0..3
  const int col  = lane & 15;
  const int grp  = lane >> 4;          // 0..3
  const int b    = blockIdx.x >> 8;    // 256 q-tiles per batch
  const int qt   = blockIdx.x & 255;
  const int qbase = qt * 16;
  const int qg = qbase + col;          // this lane's q row (S^T columns)

  __shared__ alignas(16) unsigned short plds[4][16][40];  // P re-layout (per wave)
  __shared__ float mL[4][16], lL[4][16];
  __shared__ float accL[4][16][66];    // stride 66: 2-way conflicts only

  const unsigned short* Qrow = Qb + (size_t)(b * T + qbase) * HS;
  const unsigned short* Kbb  = Kb + (size_t)b * T * HS;
  const unsigned short* Vtb  = Vt + (size_t)b * HS * T;

  const short8 qf0 = *(const short8*)(Qrow + col * HS + grp * 8);
  const short8 qf1 = *(const short8*)(Qrow + col * HS + grp * 8 + 32);

  f32x4 acc[4];
#pragma unroll
  for (int nt = 0; nt < 4; ++nt) acc[nt] = (f32x4){0.f, 0.f, 0.f, 0.f};
  float m = -INFINITY, lsum = 0.f;

  const int nkv = (qbase + 16 + 31) >> 5;   // KV blocks for this q-tile

  short8 kfA[4], vfA[4], kfB[4], vfB[4];

  auto loadKV = [&](int k0, short8 (&kd)[4], short8 (&vd)[4]) {
    const unsigned short* Kp = Kbb + (size_t)(k0 + col) * HS + grp * 8;
    kd[0] = *(const short8*)(Kp);
    kd[1] = *(const short8*)(Kp + 32);
    kd[2] = *(const short8*)(Kp + 16 * HS);
    kd[3] = *(const short8*)(Kp + 16 * HS + 32);
    const unsigned short* Vp = Vtb + (size_t)col * T + k0 + grp * 8;
    vd[0] = *(const short8*)(Vp);
    vd[1] = *(const short8*)(Vp + 16 * T);
    vd[2] = *(const short8*)(Vp + 32 * T);
    vd[3] = *(const short8*)(Vp + 48 * T);
  };

  auto step = [&](int kb, short8 (&kc)[4], short8 (&vc)[4],
                  short8 (&kn)[4], short8 (&vn)[4]) {
    const int k0 = kb * 32;
    int kp = (kb + 4) * 32;                 // this wave's next KV block
    if (kp > T - 32) kp = T - 32;           // clamp in-bounds (dup harmless)
    loadKV(kp, kn, vn);

    f32x4 s0 = (f32x4){0.f, 0.f, 0.f, 0.f};
    f32x4 s1 = (f32x4){0.f, 0.f, 0.f, 0.f};
    s0 = MFMA16(kc[0], qf0, s0);
    s0 = MFMA16(kc[1], qf1, s0);
    s1 = MFMA16(kc[2], qf0, s1);
    s1 = MFMA16(kc[3], qf1, s1);

    float pe[8];
    float pm = -INFINITY;
#pragma unroll
    for (int r = 0; r < 4; ++r) {
      const int key0 = k0 + 4 * grp + r;
      const float v0 = (key0 <= qg) ? s0[r] : -INFINITY;
      const float v1 = (key0 + 16 <= qg) ? s1[r] : -INFINITY;
      pe[r] = v0;
      pe[4 + r] = v1;
      pm = fmaxf(pm, fmaxf(v0, v1));
    }
    pm = fmaxf(pm, __shfl_xor(pm, 16, 64));
    pm = fmaxf(pm, __shfl_xor(pm, 32, 64));
    const float mn = fmaxf(m, pm);
    const float corr = __expf(m - mn);
    float ps = 0.f;
#pragma unroll
    for (int i = 0; i < 8; ++i) {
      pe[i] = __expf(pe[i] - mn);
      ps += pe[i];
    }
    ps += __shfl_xor(ps, 16, 64);
    ps += __shfl_xor(ps, 32, 64);
    lsum = lsum * corr + ps;
    m = mn;

    short4v w0, w1;
#pragma unroll
    for (int r = 0; r < 4; ++r) {
      w0[r] = (short)f2bf(pe[r]);
      w1[r] = (short)f2bf(pe[4 + r]);
    }
    *(short4v*)(&plds[w][col][4 * grp]) = w0;
    *(short4v*)(&plds[w][col][16 + 4 * grp]) = w1;
    const short8 pa = *(const short8*)(&plds[w][col][8 * grp]);

    float cr[4];
#pragma unroll
    for (int r = 0; r < 4; ++r) cr[r] = __shfl(corr, 4 * grp + r, 64);
#pragma unroll
    for (int nt = 0; nt < 4; ++nt) {
#pragma unroll
      for (int r = 0; r < 4; ++r) acc[nt][r] *= cr[r];
    }

#pragma unroll
    for (int nt = 0; nt < 4; ++nt) acc[nt] = MFMA16(pa, vc[nt], acc[nt]);
  };

  if (w < nkv) {
    loadKV(32 * w, kfA, vfA);
    for (int kb = w; kb < nkv; kb += 8) {
      step(kb, kfA, vfA, kfB, vfB);
      if (kb + 4 < nkv) step(kb + 4, kfB, vfB, kfA, vfA);
    }
  }

  // ---- cross-wave merge via LDS ----
  if (grp == 0) { mL[w][col] = m; lL[w][col] = lsum; }
  __syncthreads();

  float f[4];
#pragma unroll
  for (int r = 0; r < 4; ++r) {
    const int row = 4 * grp + r;
    const float M = fmaxf(fmaxf(mL[0][row], mL[1][row]),
                          fmaxf(mL[2][row], mL[3][row]));
    f[r] = __expf(mL[w][row] - M);    // idle wave: exp(-inf) = 0
  }
#pragma unroll
  for (int nt = 0; nt < 4; ++nt) {
#pragma unroll
    for (int r = 0; r < 4; ++r)
      accL[w][4 * grp + r][col + 16 * nt] = acc[nt][r] * f[r];
  }
  __syncthreads();

  // wave w reduces rows {4*grp + w}; 16 lanes per row cover d via col+16k
  {
    const int row = 4 * grp + w;
    const float M = fmaxf(fmaxf(mL[0][row], mL[1][row]),
                          fmaxf(mL[2][row], mL[3][row]));
    float L = 0.f;
#pragma unroll
    for (int ww = 0; ww < 4; ++ww) L += lL[ww][row] * __expf(mL[ww][row] - M);
    float* op = out + (size_t)(b * T + qbase + row) * HS;
#pragma unroll
    for (int k = 0; k < 4; ++k) {
      const int d = col + 16 * k;
      const float v = accL[0][row][d] + accL[1][row][d] +
                      accL[2][row][d] + accL[3][row][d];
      op[d] = v / L;
    }
  }
}

extern "C" void kernel_launch(void* const* d_in, const int* in_sizes, int n_in,
                              void* d_out, int out_size, void* d_ws, size_t ws_size,
                              hipStream_t stream) {
  const float* x  = (const float*)d_in[0];
  const float* Wq = (const float*)d_in[1];
  const float* bq = (const float*)d_in[2];
  const float* Wk = (const float*)d_in[3];
  const float* bk = (const float*)d_in[4];
  const float* Wv = (const float*)d_in[5];
  const float* bv = (const float*)d_in[6];
  float* out = (float*)d_out;

  unsigned short* Qb = (unsigned short*)d_ws;
  unsigned short* Kb = Qb + (size_t)B * T * HS;
  unsigned short* Vt = Kb + (size_t)B * T * HS;
  unsigned short* Wt = Vt + (size_t)B * T * HS;

  conv_w_kernel<<<192, 64, 0, stream>>>(Wq, Wk, Wv, Wt);
  proj_kernel<<<B * T / 32, 64, 0, stream>>>(x, Wt, bq, bk, bv, Qb, Kb, Vt);
  attn_kernel<<<B * (T / 16), 256, 0, stream>>>(Qb, Kb, Vt, out);
}

// Round 5
// 151.266 us; speedup vs baseline: 21.5621x; 1.0263x over previous
//
#include <hip/hip_runtime.h>
#include <hip/hip_bf16.h>
#include <math.h>

#define B 4
#define T 4096
#define C 1024
#define HS 64

typedef __attribute__((ext_vector_type(8))) short short8;
typedef __attribute__((ext_vector_type(4))) float f32x4;
typedef __attribute__((ext_vector_type(16))) float f32x16;

#define MFMA16(a, b, c) __builtin_amdgcn_mfma_f32_16x16x32_bf16((a), (b), (c), 0, 0, 0)
#define MFMA32(a, b, c) __builtin_amdgcn_mfma_f32_32x32x16_bf16((a), (b), (c), 0, 0, 0)

static __device__ __forceinline__ unsigned short f2bf(float f) {
  union { float f; unsigned u; } v; v.f = f;
  unsigned r = v.u + 0x7FFFu + ((v.u >> 16) & 1u);  // RNE to bf16
  return (unsigned short)(r >> 16);
}

static __device__ __forceinline__ unsigned pack_bf2(float lo, float hi2) {
  union { __hip_bfloat16 h; unsigned short u; } a, c;
  a.h = __float2bfloat16(lo); c.h = __float2bfloat16(hi2);
  return (unsigned)a.u | ((unsigned)c.u << 16);
}

// ---------------------------------------------------------------------------
// Kernel 0: W -> bf16 transposed Wt[n][c] via coalesced read + LDS transpose.
// 48 blocks (3 W x 16 chunks of 64 c-rows) x 256 threads.
// ---------------------------------------------------------------------------
__global__ __launch_bounds__(256) void conv_w_kernel(
    const float* __restrict__ Wq, const float* __restrict__ Wk,
    const float* __restrict__ Wv, unsigned short* __restrict__ Wt) {
  const int wi = blockIdx.x >> 4;          // 0..2
  const int c0 = (blockIdx.x & 15) * 64;
  const float* W = (wi == 0) ? Wq : (wi == 1) ? Wk : Wv;
  __shared__ float ws[64][65];
  const int t = threadIdx.x;
  const int r = t >> 2;                    // c-row within chunk
  const int cb = (t & 3) * 16;             // h-col base
#pragma unroll
  for (int j = 0; j < 4; ++j) {
    const f32x4 v = *(const f32x4*)&W[(size_t)(c0 + r) * HS + cb + 4 * j];
    ws[cb + 4 * j + 0][r] = v[0];
    ws[cb + 4 * j + 1][r] = v[1];
    ws[cb + 4 * j + 2][r] = v[2];
    ws[cb + 4 * j + 3][r] = v[3];
  }
  __syncthreads();
  const int h = t >> 2;                    // output n-row within chunk
  const int rb = (t & 3) * 16;             // c base
  union { short8 s8[2]; unsigned short u[16]; } o;
#pragma unroll
  for (int i = 0; i < 16; ++i) o.u[i] = f2bf(ws[h][rb + i]);
  short8* dst = (short8*)(Wt + (size_t)(wi * 64 + h) * C + c0 + rb);
  dst[0] = o.s8[0];
  dst[1] = o.s8[1];
}

// ---------------------------------------------------------------------------
// Kernel 1: fused QKV projection GEMM. 1024 blocks x 1 wave; wave = 16 rows x
// 192 cols; 4-deep A prefetch (named buffers, static indices).
// ---------------------------------------------------------------------------
__global__ __launch_bounds__(64) void proj_kernel(
    const float* __restrict__ x, const unsigned short* __restrict__ Wt,
    const float* __restrict__ bq, const float* __restrict__ bk,
    const float* __restrict__ bv,
    unsigned short* __restrict__ Qb, unsigned short* __restrict__ Kb,
    unsigned short* __restrict__ Vt) {
  const int m0   = blockIdx.x * 16;
  const int lane = threadIdx.x;
  const int col  = lane & 15, grp = lane >> 4;

  const float* xr = x + (size_t)(m0 + col) * C + grp * 8;

  f32x4 acc[12];
#pragma unroll
  for (int nt = 0; nt < 12; ++nt) acc[nt] = (f32x4){0.f, 0.f, 0.f, 0.f};

  auto loadA = [&](int kc, short8& a) {
    const f32x4 p0 = *(const f32x4*)(xr + kc);
    const f32x4 p1 = *(const f32x4*)(xr + kc + 4);
    short8 tv;
#pragma unroll
    for (int e = 0; e < 4; ++e) {
      tv[e] = (short)f2bf(p0[e]); tv[4 + e] = (short)f2bf(p1[e]);
    }
    a = tv;
  };

  auto stepK = [&](int kc, short8 a) {
    const unsigned short* wp = Wt + (size_t)col * C + kc + grp * 8;
#pragma unroll
    for (int nt = 0; nt < 12; ++nt) {
      const short8 bf = *(const short8*)(wp + (size_t)nt * 16 * C);
      acc[nt] = MFMA16(a, bf, acc[nt]);
    }
  };

  short8 aA, aB, aC, aD;
  loadA(0, aA); loadA(32, aB); loadA(64, aC); loadA(96, aD);
  for (int kc = 0; kc < C; kc += 128) {
    stepK(kc, aA);      if (kc + 128 < C) loadA(kc + 128, aA);
    stepK(kc + 32, aB); if (kc + 160 < C) loadA(kc + 160, aB);
    stepK(kc + 64, aC); if (kc + 192 < C) loadA(kc + 192, aC);
    stepK(kc + 96, aD); if (kc + 224 < C) loadA(kc + 224, aD);
  }

  auto writeOut = [&](int row, int n, float v) {
    if (n < 64)       Qb[(size_t)row * HS + n] = f2bf(v * 0.03125f);
    else if (n < 128) Kb[(size_t)row * HS + (n - 64)] = f2bf(v);
    else Vt[((size_t)(row >> 12) * HS + (n - 128)) * T + (row & (T - 1))] = f2bf(v);
  };
#pragma unroll
  for (int nt = 0; nt < 12; ++nt) {
    const int n = nt * 16 + col;
    const float bias = (n < 64) ? bq[n] : (n < 128) ? bk[n - 64] : bv[n - 128];
#pragma unroll
    for (int r = 0; r < 4; ++r)
      writeOut(m0 + 4 * grp + r, n, acc[nt][r] + bias);
  }
}

// ---------------------------------------------------------------------------
// Kernel 2: flash attention, 32x32 MFMA, fully swapped operands.
// 512 blocks (one per 32-row q-tile) x 4 waves; wave w: kb = w, w+4, ...
// S^T = mfma32(K, Q): lane q = lane&31 holds 32 key-scores in 16 regs (+hi).
// out^T = mfma32(V^T, P^T): accumulator q = lane&31 too -> scalar rescale.
// P^T B-frags built in-reg: 8 bf16-pair packs + 8 shfl_xor(32) + selects.
// Cross-wave merge via LDS.
// ---------------------------------------------------------------------------
__global__ __launch_bounds__(256, 2) void attn_kernel(
    const unsigned short* __restrict__ Qb,
    const unsigned short* __restrict__ Kb,
    const unsigned short* __restrict__ Vt,
    float* __restrict__ out) {
  const int lane = threadIdx.x & 63;
  const int w    = threadIdx.x >> 6;   // 0..3
  const int q    = lane & 31;
  const int hi   = lane >> 5;          // 0..1
  const int b    = blockIdx.x >> 7;    // 128 q-tiles per batch
  const int qt   = blockIdx.x & 127;
  const int qbase = qt * 32;
  const int qg    = qbase + q;

  __shared__ float accL[4][64][33];
  __shared__ float mL[4][32], lL[4][32], invL[32];

  const unsigned short* Qp  = Qb + (size_t)(b * T + qbase + q) * HS + 8 * hi;
  const unsigned short* Kbb = Kb + (size_t)b * T * HS;
  const unsigned short* Vtb = Vt + (size_t)b * HS * T;

  short8 qf[4];
#pragma unroll
  for (int j = 0; j < 4; ++j) qf[j] = *(const short8*)(Qp + 16 * j);

  f32x16 acc0, acc1;
#pragma unroll
  for (int r = 0; r < 16; ++r) { acc0[r] = 0.f; acc1[r] = 0.f; }
  float m = -INFINITY, lsum = 0.f;

  const int nkv = qt + 1;

  short8 kA[4], kB[4];

  auto loadK = [&](int k0, short8 (&kd)[4]) {
    const unsigned short* p = Kbb + (size_t)(k0 + q) * HS + 8 * hi;
    kd[0] = *(const short8*)(p);
    kd[1] = *(const short8*)(p + 16);
    kd[2] = *(const short8*)(p + 32);
    kd[3] = *(const short8*)(p + 48);
  };

  auto step = [&](int kb, short8 (&kc)[4], short8 (&kn)[4]) {
    const int k0 = kb * 32;
    // V loads (single buffer; consumed after softmax -> latency hidden)
    const unsigned short* vp = Vtb + (size_t)q * T + k0 + 8 * hi;
    const short8 v00 = *(const short8*)(vp);                 // d 0-31,  k 0-15
    const short8 v01 = *(const short8*)(vp + 16);            // d 0-31,  k 16-31
    const short8 v10 = *(const short8*)(vp + (size_t)32 * T);        // d 32-63, k 0-15
    const short8 v11 = *(const short8*)(vp + (size_t)32 * T + 16);   // d 32-63, k 16-31
    // prefetch next K block for this wave (clamped; dup harmless)
    int knx = k0 + 128;
    if (knx > T - 32) knx = T - 32;
    loadK(knx, kn);

    // ---- QK^T: S^T[key][q], contraction over c in 4 chunks of 16 ----
    f32x16 s;
#pragma unroll
    for (int r = 0; r < 16; ++r) s[r] = 0.f;
    s = MFMA32(kc[0], qf[0], s);
    s = MFMA32(kc[1], qf[1], s);
    s = MFMA32(kc[2], qf[2], s);
    s = MFMA32(kc[3], qf[3], s);

    // ---- causal mask + max (key = (r&3)+8*(r>>2)+4*hi) ----
    const int qrel = qg - k0;
    float pe[16];
#pragma unroll
    for (int r = 0; r < 16; ++r) {
      const int key = (r & 3) + 8 * (r >> 2) + 4 * hi;
      pe[r] = (key <= qrel) ? s[r] : -INFINITY;
    }
    float t0 = fmaxf(fmaxf(pe[0], pe[1]), fmaxf(pe[2], pe[3]));
    float t1 = fmaxf(fmaxf(pe[4], pe[5]), fmaxf(pe[6], pe[7]));
    float t2 = fmaxf(fmaxf(pe[8], pe[9]), fmaxf(pe[10], pe[11]));
    float t3 = fmaxf(fmaxf(pe[12], pe[13]), fmaxf(pe[14], pe[15]));
    float pm = fmaxf(fmaxf(t0, t1), fmaxf(t2, t3));
    pm = fmaxf(pm, __shfl_xor(pm, 32, 64));

    const float mn = fmaxf(m, pm);
    if (!__all(mn == m)) {            // exact defer: corr==1 when no new max
      const float corr = __expf(m - mn);
      lsum *= corr;
#pragma unroll
      for (int r = 0; r < 16; ++r) { acc0[r] *= corr; acc1[r] *= corr; }
      m = mn;
    }
    float ps = 0.f;
#pragma unroll
    for (int r = 0; r < 16; ++r) {
      pe[r] = __expf(pe[r] - m);
      ps += pe[r];
    }
    ps += __shfl_xor(ps, 32, 64);
    lsum += ps;

    // ---- P^T -> bf16 B-fragments (in-register, shfl exchange) ----
    unsigned own[8], oth[8];
#pragma unroll
    for (int j = 0; j < 8; ++j) own[j] = pack_bf2(pe[2 * j], pe[2 * j + 1]);
#pragma unroll
    for (int j = 0; j < 8; ++j) oth[j] = __shfl_xor(own[j], 32, 64);
    union U { short8 s8; unsigned u[4]; };
    U p0, p1;
    p0.u[0] = hi ? oth[2] : own[0];
    p0.u[1] = hi ? oth[3] : own[1];
    p0.u[2] = hi ? own[2] : oth[0];
    p0.u[3] = hi ? own[3] : oth[1];
    p1.u[0] = hi ? oth[6] : own[4];
    p1.u[1] = hi ? oth[7] : own[5];
    p1.u[2] = hi ? own[6] : oth[4];
    p1.u[3] = hi ? own[7] : oth[5];

    // ---- PV: out^T[d][q] += V^T[d][k] P^T[k][q] ----
    acc0 = MFMA32(v00, p0.s8, acc0);
    acc0 = MFMA32(v01, p1.s8, acc0);
    acc1 = MFMA32(v10, p0.s8, acc1);
    acc1 = MFMA32(v11, p1.s8, acc1);
  };

  if (w < nkv) {
    loadK(32 * w, kA);
    int kb = w;
    while (true) {
      step(kb, kA, kB); kb += 4; if (kb >= nkv) break;
      step(kb, kB, kA); kb += 4; if (kb >= nkv) break;
    }
  }

  // ---- cross-wave merge ----
  if (hi == 0) { mL[w][q] = m; lL[w][q] = lsum; }
  __syncthreads();
  {
    const float Mv = fmaxf(fmaxf(mL[0][q], mL[1][q]), fmaxf(mL[2][q], mL[3][q]));
    const float f = __expf(m - Mv);   // idle wave: exp(-inf)=0
#pragma unroll
    for (int r = 0; r < 16; ++r) {
      const int d = (r & 3) + 8 * (r >> 2) + 4 * hi;
      accL[w][d][q]      = acc0[r] * f;
      accL[w][d + 32][q] = acc1[r] * f;
    }
  }
  __syncthreads();
  if (threadIdx.x < 32) {
    const int qq = threadIdx.x;
    const float Mv = fmaxf(fmaxf(mL[0][qq], mL[1][qq]), fmaxf(mL[2][qq], mL[3][qq]));
    float L = 0.f;
#pragma unroll
    for (int ww = 0; ww < 4; ++ww) L += lL[ww][qq] * __expf(mL[ww][qq] - Mv);
    invL[qq] = 1.f / L;
  }
  __syncthreads();
#pragma unroll
  for (int p = 0; p < 8; ++p) {
    const int qq = (threadIdx.x >> 6) + 4 * p;
    const int d  = threadIdx.x & 63;
    const float v = accL[0][d][qq] + accL[1][d][qq] +
                    accL[2][d][qq] + accL[3][d][qq];
    out[(size_t)(b * T + qbase + qq) * HS + d] = v * invL[qq];
  }
}

extern "C" void kernel_launch(void* const* d_in, const int* in_sizes, int n_in,
                              void* d_out, int out_size, void* d_ws, size_t ws_size,
                              hipStream_t stream) {
  const float* x  = (const float*)d_in[0];
  const float* Wq = (const float*)d_in[1];
  const float* bq = (const float*)d_in[2];
  const float* Wk = (const float*)d_in[3];
  const float* bk = (const float*)d_in[4];
  const float* Wv = (const float*)d_in[5];
  const float* bv = (const float*)d_in[6];
  float* out = (float*)d_out;

  unsigned short* Qb = (unsigned short*)d_ws;
  unsigned short* Kb = Qb + (size_t)B * T * HS;
  unsigned short* Vt = Kb + (size_t)B * T * HS;
  unsigned short* Wt = Vt + (size_t)B * T * HS;

  conv_w_kernel<<<48, 256, 0, stream>>>(Wq, Wk, Wv, Wt);
  proj_kernel<<<B * T / 16, 64, 0, stream>>>(x, Wt, bq, bk, bv, Qb, Kb, Vt);
  attn_kernel<<<B * (T / 32), 256, 0, stream>>>(Qb, Kb, Vt, out);
}

// Round 6
// 144.367 us; speedup vs baseline: 22.5926x; 1.0478x over previous
//
#include <hip/hip_runtime.h>
#include <hip/hip_bf16.h>
#include <math.h>

#define B 4
#define T 4096
#define C 1024
#define HS 64

typedef __attribute__((ext_vector_type(8))) short short8;
typedef __attribute__((ext_vector_type(4))) float f32x4;
typedef __attribute__((ext_vector_type(16))) float f32x16;

#define MFMA16(a, b, c) __builtin_amdgcn_mfma_f32_16x16x32_bf16((a), (b), (c), 0, 0, 0)
#define MFMA32(a, b, c) __builtin_amdgcn_mfma_f32_32x32x16_bf16((a), (b), (c), 0, 0, 0)

static __device__ __forceinline__ unsigned short f2bf(float f) {
  union { float f; unsigned u; } v; v.f = f;
  unsigned r = v.u + 0x7FFFu + ((v.u >> 16) & 1u);  // RNE to bf16
  return (unsigned short)(r >> 16);
}

static __device__ __forceinline__ unsigned pack_bf2(float lo, float hi2) {
  union { __hip_bfloat16 h; unsigned short u; } a, c;
  a.h = __float2bfloat16(lo); c.h = __float2bfloat16(hi2);
  return (unsigned)a.u | ((unsigned)c.u << 16);
}

// ---------------------------------------------------------------------------
// Kernel 0: W -> bf16 transposed Wt[n][c] via coalesced read + LDS transpose.
// ---------------------------------------------------------------------------
__global__ __launch_bounds__(256) void conv_w_kernel(
    const float* __restrict__ Wq, const float* __restrict__ Wk,
    const float* __restrict__ Wv, unsigned short* __restrict__ Wt) {
  const int wi = blockIdx.x >> 4;          // 0..2
  const int c0 = (blockIdx.x & 15) * 64;
  const float* W = (wi == 0) ? Wq : (wi == 1) ? Wk : Wv;
  __shared__ float ws[64][65];
  const int t = threadIdx.x;
  const int r = t >> 2;                    // c-row within chunk
  const int cb = (t & 3) * 16;             // h-col base
#pragma unroll
  for (int j = 0; j < 4; ++j) {
    const f32x4 v = *(const f32x4*)&W[(size_t)(c0 + r) * HS + cb + 4 * j];
    ws[cb + 4 * j + 0][r] = v[0];
    ws[cb + 4 * j + 1][r] = v[1];
    ws[cb + 4 * j + 2][r] = v[2];
    ws[cb + 4 * j + 3][r] = v[3];
  }
  __syncthreads();
  const int h = t >> 2;                    // output n-row within chunk
  const int rb = (t & 3) * 16;             // c base
  union { short8 s8[2]; unsigned short u[16]; } o;
#pragma unroll
  for (int i = 0; i < 16; ++i) o.u[i] = f2bf(ws[h][rb + i]);
  short8* dst = (short8*)(Wt + (size_t)(wi * 64 + h) * C + c0 + rb);
  dst[0] = o.s8[0];
  dst[1] = o.s8[1];
}

// ---------------------------------------------------------------------------
// Kernel 1: fused QKV projection GEMM.
// 1024 blocks x 4 waves (256 thr). Block = 16 rows; wave w = N-cols 48w..48w+47
// (3 N-tiles). All waves share the block's A-chunk via L1 (2KB/step window).
// 4-deep A prefetch, named buffers (static indices). 4096 waves = 4/SIMD.
// ---------------------------------------------------------------------------
__global__ __launch_bounds__(256) void proj_kernel(
    const float* __restrict__ x, const unsigned short* __restrict__ Wt,
    const float* __restrict__ bq, const float* __restrict__ bk,
    const float* __restrict__ bv,
    unsigned short* __restrict__ Qb, unsigned short* __restrict__ Kb,
    unsigned short* __restrict__ Vt) {
  const int m0   = blockIdx.x * 16;
  const int w    = threadIdx.x >> 6;   // 0..3: N-group
  const int lane = threadIdx.x & 63;
  const int col  = lane & 15, grp = lane >> 4;
  const int n0   = w * 48;

  const float* xr = x + (size_t)(m0 + col) * C + grp * 8;

  f32x4 acc[3];
#pragma unroll
  for (int nt = 0; nt < 3; ++nt) acc[nt] = (f32x4){0.f, 0.f, 0.f, 0.f};

  auto loadA = [&](int kc, short8& a) {
    const f32x4 p0 = *(const f32x4*)(xr + kc);
    const f32x4 p1 = *(const f32x4*)(xr + kc + 4);
    short8 tv;
#pragma unroll
    for (int e = 0; e < 4; ++e) {
      tv[e] = (short)f2bf(p0[e]); tv[4 + e] = (short)f2bf(p1[e]);
    }
    a = tv;
  };

  auto stepK = [&](int kc, short8 a) {
    const unsigned short* wp = Wt + (size_t)(n0 + col) * C + kc + grp * 8;
#pragma unroll
    for (int nt = 0; nt < 3; ++nt) {
      const short8 bf = *(const short8*)(wp + (size_t)nt * 16 * C);
      acc[nt] = MFMA16(a, bf, acc[nt]);
    }
  };

  short8 aA, aB, aC, aD;
  loadA(0, aA); loadA(32, aB); loadA(64, aC); loadA(96, aD);
  for (int kc = 0; kc < C; kc += 128) {
    stepK(kc, aA);      if (kc + 128 < C) loadA(kc + 128, aA);
    stepK(kc + 32, aB); if (kc + 160 < C) loadA(kc + 160, aB);
    stepK(kc + 64, aC); if (kc + 192 < C) loadA(kc + 192, aC);
    stepK(kc + 96, aD); if (kc + 224 < C) loadA(kc + 224, aD);
  }

  auto writeOut = [&](int row, int n, float v) {
    if (n < 64)       Qb[(size_t)row * HS + n] = f2bf(v * 0.03125f);
    else if (n < 128) Kb[(size_t)row * HS + (n - 64)] = f2bf(v);
    else Vt[((size_t)(row >> 12) * HS + (n - 128)) * T + (row & (T - 1))] = f2bf(v);
  };
#pragma unroll
  for (int nt = 0; nt < 3; ++nt) {
    const int n = n0 + nt * 16 + col;
    const float bias = (n < 64) ? bq[n] : (n < 128) ? bk[n - 64] : bv[n - 128];
#pragma unroll
    for (int r = 0; r < 4; ++r)
      writeOut(m0 + 4 * grp + r, n, acc[nt][r] + bias);
  }
}

// ---------------------------------------------------------------------------
// Kernel 2: flash attention, 32x32 MFMA, fully swapped operands (unchanged).
// ---------------------------------------------------------------------------
__global__ __launch_bounds__(256, 2) void attn_kernel(
    const unsigned short* __restrict__ Qb,
    const unsigned short* __restrict__ Kb,
    const unsigned short* __restrict__ Vt,
    float* __restrict__ out) {
  const int lane = threadIdx.x & 63;
  const int w    = threadIdx.x >> 6;   // 0..3
  const int q    = lane & 31;
  const int hi   = lane >> 5;          // 0..1
  const int b    = blockIdx.x >> 7;    // 128 q-tiles per batch
  const int qt   = blockIdx.x & 127;
  const int qbase = qt * 32;
  const int qg    = qbase + q;

  __shared__ float accL[4][64][33];
  __shared__ float mL[4][32], lL[4][32], invL[32];

  const unsigned short* Qp  = Qb + (size_t)(b * T + qbase + q) * HS + 8 * hi;
  const unsigned short* Kbb = Kb + (size_t)b * T * HS;
  const unsigned short* Vtb = Vt + (size_t)b * HS * T;

  short8 qf[4];
#pragma unroll
  for (int j = 0; j < 4; ++j) qf[j] = *(const short8*)(Qp + 16 * j);

  f32x16 acc0, acc1;
#pragma unroll
  for (int r = 0; r < 16; ++r) { acc0[r] = 0.f; acc1[r] = 0.f; }
  float m = -INFINITY, lsum = 0.f;

  const int nkv = qt + 1;

  short8 kA[4], kB[4];

  auto loadK = [&](int k0, short8 (&kd)[4]) {
    const unsigned short* p = Kbb + (size_t)(k0 + q) * HS + 8 * hi;
    kd[0] = *(const short8*)(p);
    kd[1] = *(const short8*)(p + 16);
    kd[2] = *(const short8*)(p + 32);
    kd[3] = *(const short8*)(p + 48);
  };

  auto step = [&](int kb, short8 (&kc)[4], short8 (&kn)[4]) {
    const int k0 = kb * 32;
    const unsigned short* vp = Vtb + (size_t)q * T + k0 + 8 * hi;
    const short8 v00 = *(const short8*)(vp);
    const short8 v01 = *(const short8*)(vp + 16);
    const short8 v10 = *(const short8*)(vp + (size_t)32 * T);
    const short8 v11 = *(const short8*)(vp + (size_t)32 * T + 16);
    int knx = k0 + 128;
    if (knx > T - 32) knx = T - 32;
    loadK(knx, kn);

    f32x16 s;
#pragma unroll
    for (int r = 0; r < 16; ++r) s[r] = 0.f;
    s = MFMA32(kc[0], qf[0], s);
    s = MFMA32(kc[1], qf[1], s);
    s = MFMA32(kc[2], qf[2], s);
    s = MFMA32(kc[3], qf[3], s);

    const int qrel = qg - k0;
    float pe[16];
#pragma unroll
    for (int r = 0; r < 16; ++r) {
      const int key = (r & 3) + 8 * (r >> 2) + 4 * hi;
      pe[r] = (key <= qrel) ? s[r] : -INFINITY;
    }
    float t0 = fmaxf(fmaxf(pe[0], pe[1]), fmaxf(pe[2], pe[3]));
    float t1 = fmaxf(fmaxf(pe[4], pe[5]), fmaxf(pe[6], pe[7]));
    float t2 = fmaxf(fmaxf(pe[8], pe[9]), fmaxf(pe[10], pe[11]));
    float t3 = fmaxf(fmaxf(pe[12], pe[13]), fmaxf(pe[14], pe[15]));
    float pm = fmaxf(fmaxf(t0, t1), fmaxf(t2, t3));
    pm = fmaxf(pm, __shfl_xor(pm, 32, 64));

    const float mn = fmaxf(m, pm);
    if (!__all(mn == m)) {
      const float corr = __expf(m - mn);
      lsum *= corr;
#pragma unroll
      for (int r = 0; r < 16; ++r) { acc0[r] *= corr; acc1[r] *= corr; }
      m = mn;
    }
    float ps = 0.f;
#pragma unroll
    for (int r = 0; r < 16; ++r) {
      pe[r] = __expf(pe[r] - m);
      ps += pe[r];
    }
    ps += __shfl_xor(ps, 32, 64);
    lsum += ps;

    unsigned own[8], oth[8];
#pragma unroll
    for (int j = 0; j < 8; ++j) own[j] = pack_bf2(pe[2 * j], pe[2 * j + 1]);
#pragma unroll
    for (int j = 0; j < 8; ++j) oth[j] = __shfl_xor(own[j], 32, 64);
    union U { short8 s8; unsigned u[4]; };
    U p0, p1;
    p0.u[0] = hi ? oth[2] : own[0];
    p0.u[1] = hi ? oth[3] : own[1];
    p0.u[2] = hi ? own[2] : oth[0];
    p0.u[3] = hi ? own[3] : oth[1];
    p1.u[0] = hi ? oth[6] : own[4];
    p1.u[1] = hi ? oth[7] : own[5];
    p1.u[2] = hi ? own[6] : oth[4];
    p1.u[3] = hi ? own[7] : oth[5];

    acc0 = MFMA32(v00, p0.s8, acc0);
    acc0 = MFMA32(v01, p1.s8, acc0);
    acc1 = MFMA32(v10, p0.s8, acc1);
    acc1 = MFMA32(v11, p1.s8, acc1);
  };

  if (w < nkv) {
    loadK(32 * w, kA);
    int kb = w;
    while (true) {
      step(kb, kA, kB); kb += 4; if (kb >= nkv) break;
      step(kb, kB, kA); kb += 4; if (kb >= nkv) break;
    }
  }

  if (hi == 0) { mL[w][q] = m; lL[w][q] = lsum; }
  __syncthreads();
  {
    const float Mv = fmaxf(fmaxf(mL[0][q], mL[1][q]), fmaxf(mL[2][q], mL[3][q]));
    const float f = __expf(m - Mv);
#pragma unroll
    for (int r = 0; r < 16; ++r) {
      const int d = (r & 3) + 8 * (r >> 2) + 4 * hi;
      accL[w][d][q]      = acc0[r] * f;
      accL[w][d + 32][q] = acc1[r] * f;
    }
  }
  __syncthreads();
  if (threadIdx.x < 32) {
    const int qq = threadIdx.x;
    const float Mv = fmaxf(fmaxf(mL[0][qq], mL[1][qq]), fmaxf(mL[2][qq], mL[3][qq]));
    float L = 0.f;
#pragma unroll
    for (int ww = 0; ww < 4; ++ww) L += lL[ww][qq] * __expf(mL[ww][qq] - Mv);
    invL[qq] = 1.f / L;
  }
  __syncthreads();
#pragma unroll
  for (int p = 0; p < 8; ++p) {
    const int qq = (threadIdx.x >> 6) + 4 * p;
    const int d  = threadIdx.x & 63;
    const float v = accL[0][d][qq] + accL[1][d][qq] +
                    accL[2][d][qq] + accL[3][d][qq];
    out[(size_t)(b * T + qbase + qq) * HS + d] = v * invL[qq];
  }
}

extern "C" void kernel_launch(void* const* d_in, const int* in_sizes, int n_in,
                              void* d_out, int out_size, void* d_ws, size_t ws_size,
                              hipStream_t stream) {
  const float* x  = (const float*)d_in[0];
  const float* Wq = (const float*)d_in[1];
  const float* bq = (const float*)d_in[2];
  const float* Wk = (const float*)d_in[3];
  const float* bk = (const float*)d_in[4];
  const float* Wv = (const float*)d_in[5];
  const float* bv = (const float*)d_in[6];
  float* out = (float*)d_out;

  unsigned short* Qb = (unsigned short*)d_ws;
  unsigned short* Kb = Qb + (size_t)B * T * HS;
  unsigned short* Vt = Kb + (size_t)B * T * HS;
  unsigned short* Wt = Vt + (size_t)B * T * HS;

  conv_w_kernel<<<48, 256, 0, stream>>>(Wq, Wk, Wv, Wt);
  proj_kernel<<<B * T / 16, 256, 0, stream>>>(x, Wt, bq, bk, bv, Qb, Kb, Vt);
  attn_kernel<<<B * (T / 32), 256, 0, stream>>>(Qb, Kb, Vt, out);
}

// Round 7
// 128.160 us; speedup vs baseline: 25.4497x; 1.1265x over previous
//
#include <hip/hip_runtime.h>
#include <hip/hip_bf16.h>
#include <math.h>

#define B 4
#define T 4096
#define C 1024
#define HS 64

typedef __attribute__((ext_vector_type(8))) short short8;
typedef __attribute__((ext_vector_type(4))) float f32x4;
typedef __attribute__((ext_vector_type(16))) float f32x16;

#define MFMA16(a, b, c) __builtin_amdgcn_mfma_f32_16x16x32_bf16((a), (b), (c), 0, 0, 0)
#define MFMA32(a, b, c) __builtin_amdgcn_mfma_f32_32x32x16_bf16((a), (b), (c), 0, 0, 0)

static __device__ __forceinline__ unsigned short f2bf(float f) {
  union { float f; unsigned u; } v; v.f = f;
  unsigned r = v.u + 0x7FFFu + ((v.u >> 16) & 1u);  // RNE to bf16
  return (unsigned short)(r >> 16);
}

static __device__ __forceinline__ unsigned pack_bf2(float lo, float hi2) {
  union { __hip_bfloat16 h; unsigned short u; } a, c;
  a.h = __float2bfloat16(lo); c.h = __float2bfloat16(hi2);
  return (unsigned)a.u | ((unsigned)c.u << 16);
}

// ---------------------------------------------------------------------------
// Kernel 0: W -> bf16 transposed Wt[n][c] via coalesced read + LDS transpose.
// ---------------------------------------------------------------------------
__global__ __launch_bounds__(256) void conv_w_kernel(
    const float* __restrict__ Wq, const float* __restrict__ Wk,
    const float* __restrict__ Wv, unsigned short* __restrict__ Wt) {
  const int wi = blockIdx.x >> 4;          // 0..2
  const int c0 = (blockIdx.x & 15) * 64;
  const float* W = (wi == 0) ? Wq : (wi == 1) ? Wk : Wv;
  __shared__ float ws[64][65];
  const int t = threadIdx.x;
  const int r = t >> 2;                    // c-row within chunk
  const int cb = (t & 3) * 16;             // h-col base
#pragma unroll
  for (int j = 0; j < 4; ++j) {
    const f32x4 v = *(const f32x4*)&W[(size_t)(c0 + r) * HS + cb + 4 * j];
    ws[cb + 4 * j + 0][r] = v[0];
    ws[cb + 4 * j + 1][r] = v[1];
    ws[cb + 4 * j + 2][r] = v[2];
    ws[cb + 4 * j + 3][r] = v[3];
  }
  __syncthreads();
  const int h = t >> 2;                    // output n-row within chunk
  const int rb = (t & 3) * 16;             // c base
  union { short8 s8[2]; unsigned short u[16]; } o;
#pragma unroll
  for (int i = 0; i < 16; ++i) o.u[i] = f2bf(ws[h][rb + i]);
  short8* dst = (short8*)(Wt + (size_t)(wi * 64 + h) * C + c0 + rb);
  dst[0] = o.s8[0];
  dst[1] = o.s8[1];
}

// ---------------------------------------------------------------------------
// Kernel 1: fused QKV projection GEMM, v3.
// 512 blocks (BM=32) x 8 waves. Per K-step (BK=64) the block stages all 24
// B-fragments (192 cols x 64 k) into LDS ONCE via global_load_lds width=16,
// fragment-ordered [frag][lane*16B] (per-lane global src, linear LDS dest).
// Double-buffered; __syncthreads provides the vmcnt drain. Per-block K-phase
// skew decorrelates the Wt sweep across blocks (kills L2 line hot-spot).
// Wave (wm,wn): rows m0+wm*16..+15, cols wn*48..+47 (3 N-frags).
// A: x fp32 global->reg, 1-iter-ahead named-buffer prefetch, cvt in-reg.
// ---------------------------------------------------------------------------
__global__ __launch_bounds__(512, 4) void proj_kernel(
    const float* __restrict__ x, const unsigned short* __restrict__ Wt,
    const float* __restrict__ bq, const float* __restrict__ bk,
    const float* __restrict__ bv,
    unsigned short* __restrict__ Qb, unsigned short* __restrict__ Kb,
    unsigned short* __restrict__ Vt) {
  const int m0   = blockIdx.x * 32;
  const int w    = threadIdx.x >> 6;   // 0..7
  const int lane = threadIdx.x & 63;
  const int col  = lane & 15, grp = lane >> 4;
  const int wm   = w >> 2;             // 0..1 row half
  const int wn   = w & 3;              // 0..3 col group
  const int phase = blockIdx.x & 15;

  __shared__ unsigned short B_lds[2][24][512];  // [buf][frag=k32*12+nt][lane*8]

  const float* xr = x + (size_t)(m0 + wm * 16 + col) * C + grp * 8;

  f32x4 acc[3];
#pragma unroll
  for (int jj = 0; jj < 3; ++jj) acc[jj] = (f32x4){0.f, 0.f, 0.f, 0.f};

  auto kcOf = [&](int it) { return ((it + phase) & 15) * 64; };

  // stage this wave's 3 fragments of the 24 into B_lds[nb]
  auto stageB = [&](int nb, int kc) {
#pragma unroll
    for (int j = 0; j < 3; ++j) {
      const int f   = w * 3 + j;
      const int nt  = f % 12;
      const int k32 = f / 12;
      const unsigned short* src =
          Wt + (size_t)(nt * 16 + col) * C + kc + k32 * 32 + grp * 8;
      __builtin_amdgcn_global_load_lds(
          (const __attribute__((address_space(1))) void*)src,
          (__attribute__((address_space(3))) void*)&B_lds[nb][f][0],
          16, 0, 0);
    }
  };

  f32x4 aC0, aC1, aC2, aC3, aN0, aN1, aN2, aN3;
  auto loadA = [&](int kc, f32x4& r0, f32x4& r1, f32x4& r2, f32x4& r3) {
    r0 = *(const f32x4*)(xr + kc);
    r1 = *(const f32x4*)(xr + kc + 4);
    r2 = *(const f32x4*)(xr + kc + 32);
    r3 = *(const f32x4*)(xr + kc + 36);
  };
  auto cvtA = [&](const f32x4& r0, const f32x4& r1) {
    short8 t;
#pragma unroll
    for (int e = 0; e < 4; ++e) {
      t[e] = (short)f2bf(r0[e]);
      t[4 + e] = (short)f2bf(r1[e]);
    }
    return t;
  };

  stageB(0, kcOf(0));
  loadA(kcOf(0), aC0, aC1, aC2, aC3);
  __syncthreads();

  for (int it = 0; it < 16; ++it) {
    const int buf = it & 1;
    if (it < 15) {
      stageB(buf ^ 1, kcOf(it + 1));
      loadA(kcOf(it + 1), aN0, aN1, aN2, aN3);
    }
    const short8 a0 = cvtA(aC0, aC1);   // k32=0
    const short8 a1 = cvtA(aC2, aC3);   // k32=1
#pragma unroll
    for (int jj = 0; jj < 3; ++jj) {
      const int ntg = wn * 3 + jj;
      const short8 b0 = *(const short8*)&B_lds[buf][ntg][(size_t)lane * 8];
      const short8 b1 = *(const short8*)&B_lds[buf][12 + ntg][(size_t)lane * 8];
      acc[jj] = MFMA16(a0, b0, acc[jj]);
      acc[jj] = MFMA16(a1, b1, acc[jj]);
    }
    __syncthreads();                    // compiler emits vmcnt(0) drain here
    if (it < 15) { aC0 = aN0; aC1 = aN1; aC2 = aN2; aC3 = aN3; }
  }

  auto writeOut = [&](int row, int n, float v) {
    if (n < 64)       Qb[(size_t)row * HS + n] = f2bf(v * 0.03125f);
    else if (n < 128) Kb[(size_t)row * HS + (n - 64)] = f2bf(v);
    else Vt[((size_t)(row >> 12) * HS + (n - 128)) * T + (row & (T - 1))] = f2bf(v);
  };
#pragma unroll
  for (int jj = 0; jj < 3; ++jj) {
    const int n = wn * 48 + jj * 16 + col;
    const float bias = (n < 64) ? bq[n] : (n < 128) ? bk[n - 64] : bv[n - 128];
#pragma unroll
    for (int r = 0; r < 4; ++r)
      writeOut(m0 + wm * 16 + 4 * grp + r, n, acc[jj][r] + bias);
  }
}

// ---------------------------------------------------------------------------
// Kernel 2: flash attention, 32x32 MFMA, fully swapped operands (unchanged).
// ---------------------------------------------------------------------------
__global__ __launch_bounds__(256, 2) void attn_kernel(
    const unsigned short* __restrict__ Qb,
    const unsigned short* __restrict__ Kb,
    const unsigned short* __restrict__ Vt,
    float* __restrict__ out) {
  const int lane = threadIdx.x & 63;
  const int w    = threadIdx.x >> 6;   // 0..3
  const int q    = lane & 31;
  const int hi   = lane >> 5;          // 0..1
  const int b    = blockIdx.x >> 7;    // 128 q-tiles per batch
  const int qt   = blockIdx.x & 127;
  const int qbase = qt * 32;
  const int qg    = qbase + q;

  __shared__ float accL[4][64][33];
  __shared__ float mL[4][32], lL[4][32], invL[32];

  const unsigned short* Qp  = Qb + (size_t)(b * T + qbase + q) * HS + 8 * hi;
  const unsigned short* Kbb = Kb + (size_t)b * T * HS;
  const unsigned short* Vtb = Vt + (size_t)b * HS * T;

  short8 qf[4];
#pragma unroll
  for (int j = 0; j < 4; ++j) qf[j] = *(const short8*)(Qp + 16 * j);

  f32x16 acc0, acc1;
#pragma unroll
  for (int r = 0; r < 16; ++r) { acc0[r] = 0.f; acc1[r] = 0.f; }
  float m = -INFINITY, lsum = 0.f;

  const int nkv = qt + 1;

  short8 kA[4], kB[4];

  auto loadK = [&](int k0, short8 (&kd)[4]) {
    const unsigned short* p = Kbb + (size_t)(k0 + q) * HS + 8 * hi;
    kd[0] = *(const short8*)(p);
    kd[1] = *(const short8*)(p + 16);
    kd[2] = *(const short8*)(p + 32);
    kd[3] = *(const short8*)(p + 48);
  };

  auto step = [&](int kb, short8 (&kc)[4], short8 (&kn)[4]) {
    const int k0 = kb * 32;
    const unsigned short* vp = Vtb + (size_t)q * T + k0 + 8 * hi;
    const short8 v00 = *(const short8*)(vp);
    const short8 v01 = *(const short8*)(vp + 16);
    const short8 v10 = *(const short8*)(vp + (size_t)32 * T);
    const short8 v11 = *(const short8*)(vp + (size_t)32 * T + 16);
    int knx = k0 + 128;
    if (knx > T - 32) knx = T - 32;
    loadK(knx, kn);

    f32x16 s;
#pragma unroll
    for (int r = 0; r < 16; ++r) s[r] = 0.f;
    s = MFMA32(kc[0], qf[0], s);
    s = MFMA32(kc[1], qf[1], s);
    s = MFMA32(kc[2], qf[2], s);
    s = MFMA32(kc[3], qf[3], s);

    const int qrel = qg - k0;
    float pe[16];
#pragma unroll
    for (int r = 0; r < 16; ++r) {
      const int key = (r & 3) + 8 * (r >> 2) + 4 * hi;
      pe[r] = (key <= qrel) ? s[r] : -INFINITY;
    }
    float t0 = fmaxf(fmaxf(pe[0], pe[1]), fmaxf(pe[2], pe[3]));
    float t1 = fmaxf(fmaxf(pe[4], pe[5]), fmaxf(pe[6], pe[7]));
    float t2 = fmaxf(fmaxf(pe[8], pe[9]), fmaxf(pe[10], pe[11]));
    float t3 = fmaxf(fmaxf(pe[12], pe[13]), fmaxf(pe[14], pe[15]));
    float pm = fmaxf(fmaxf(t0, t1), fmaxf(t2, t3));
    pm = fmaxf(pm, __shfl_xor(pm, 32, 64));

    const float mn = fmaxf(m, pm);
    if (!__all(mn == m)) {
      const float corr = __expf(m - mn);
      lsum *= corr;
#pragma unroll
      for (int r = 0; r < 16; ++r) { acc0[r] *= corr; acc1[r] *= corr; }
      m = mn;
    }
    float ps = 0.f;
#pragma unroll
    for (int r = 0; r < 16; ++r) {
      pe[r] = __expf(pe[r] - m);
      ps += pe[r];
    }
    ps += __shfl_xor(ps, 32, 64);
    lsum += ps;

    unsigned own[8], oth[8];
#pragma unroll
    for (int j = 0; j < 8; ++j) own[j] = pack_bf2(pe[2 * j], pe[2 * j + 1]);
#pragma unroll
    for (int j = 0; j < 8; ++j) oth[j] = __shfl_xor(own[j], 32, 64);
    union U { short8 s8; unsigned u[4]; };
    U p0, p1;
    p0.u[0] = hi ? oth[2] : own[0];
    p0.u[1] = hi ? oth[3] : own[1];
    p0.u[2] = hi ? own[2] : oth[0];
    p0.u[3] = hi ? own[3] : oth[1];
    p1.u[0] = hi ? oth[6] : own[4];
    p1.u[1] = hi ? oth[7] : own[5];
    p1.u[2] = hi ? own[6] : oth[4];
    p1.u[3] = hi ? own[7] : oth[5];

    acc0 = MFMA32(v00, p0.s8, acc0);
    acc0 = MFMA32(v01, p1.s8, acc0);
    acc1 = MFMA32(v10, p0.s8, acc1);
    acc1 = MFMA32(v11, p1.s8, acc1);
  };

  if (w < nkv) {
    loadK(32 * w, kA);
    int kb = w;
    while (true) {
      step(kb, kA, kB); kb += 4; if (kb >= nkv) break;
      step(kb, kB, kA); kb += 4; if (kb >= nkv) break;
    }
  }

  if (hi == 0) { mL[w][q] = m; lL[w][q] = lsum; }
  __syncthreads();
  {
    const float Mv = fmaxf(fmaxf(mL[0][q], mL[1][q]), fmaxf(mL[2][q], mL[3][q]));
    const float f = __expf(m - Mv);
#pragma unroll
    for (int r = 0; r < 16; ++r) {
      const int d = (r & 3) + 8 * (r >> 2) + 4 * hi;
      accL[w][d][q]      = acc0[r] * f;
      accL[w][d + 32][q] = acc1[r] * f;
    }
  }
  __syncthreads();
  if (threadIdx.x < 32) {
    const int qq = threadIdx.x;
    const float Mv = fmaxf(fmaxf(mL[0][qq], mL[1][qq]), fmaxf(mL[2][qq], mL[3][qq]));
    float L = 0.f;
#pragma unroll
    for (int ww = 0; ww < 4; ++ww) L += lL[ww][qq] * __expf(mL[ww][qq] - Mv);
    invL[qq] = 1.f / L;
  }
  __syncthreads();
#pragma unroll
  for (int p = 0; p < 8; ++p) {
    const int qq = (threadIdx.x >> 6) + 4 * p;
    const int d  = threadIdx.x & 63;
    const float v = accL[0][d][qq] + accL[1][d][qq] +
                    accL[2][d][qq] + accL[3][d][qq];
    out[(size_t)(b * T + qbase + qq) * HS + d] = v * invL[qq];
  }
}

extern "C" void kernel_launch(void* const* d_in, const int* in_sizes, int n_in,
                              void* d_out, int out_size, void* d_ws, size_t ws_size,
                              hipStream_t stream) {
  const float* x  = (const float*)d_in[0];
  const float* Wq = (const float*)d_in[1];
  const float* bq = (const float*)d_in[2];
  const float* Wk = (const float*)d_in[3];
  const float* bk = (const float*)d_in[4];
  const float* Wv = (const float*)d_in[5];
  const float* bv = (const float*)d_in[6];
  float* out = (float*)d_out;

  unsigned short* Qb = (unsigned short*)d_ws;
  unsigned short* Kb = Qb + (size_t)B * T * HS;
  unsigned short* Vt = Kb + (size_t)B * T * HS;
  unsigned short* Wt = Vt + (size_t)B * T * HS;

  conv_w_kernel<<<48, 256, 0, stream>>>(Wq, Wk, Wv, Wt);
  proj_kernel<<<B * T / 32, 512, 0, stream>>>(x, Wt, bq, bk, bv, Qb, Kb, Vt);
  attn_kernel<<<B * (T / 32), 256, 0, stream>>>(Qb, Kb, Vt, out);
}

// Round 8
// 93.913 us; speedup vs baseline: 34.7303x; 1.3647x over previous
//
#include <hip/hip_runtime.h>
#include <hip/hip_bf16.h>
#include <math.h>

#define B 4
#define T 4096
#define C 1024
#define HS 64

typedef __attribute__((ext_vector_type(8))) short short8;
typedef __attribute__((ext_vector_type(4))) float f32x4;
typedef __attribute__((ext_vector_type(16))) float f32x16;

#define MFMA16(a, b, c) __builtin_amdgcn_mfma_f32_16x16x32_bf16((a), (b), (c), 0, 0, 0)
#define MFMA32(a, b, c) __builtin_amdgcn_mfma_f32_32x32x16_bf16((a), (b), (c), 0, 0, 0)

static __device__ __forceinline__ unsigned short f2bf(float f) {
  union { float f; unsigned u; } v; v.f = f;
  unsigned r = v.u + 0x7FFFu + ((v.u >> 16) & 1u);  // RNE to bf16
  return (unsigned short)(r >> 16);
}

static __device__ __forceinline__ unsigned pack_bf2(float lo, float hi2) {
  union { __hip_bfloat16 h; unsigned short u; } a, c;
  a.h = __float2bfloat16(lo); c.h = __float2bfloat16(hi2);
  return (unsigned)a.u | ((unsigned)c.u << 16);
}

// ---------------------------------------------------------------------------
// Kernel 0: W -> bf16 transposed Wt[n][c] via coalesced read + LDS transpose.
// ---------------------------------------------------------------------------
__global__ __launch_bounds__(256) void conv_w_kernel(
    const float* __restrict__ Wq, const float* __restrict__ Wk,
    const float* __restrict__ Wv, unsigned short* __restrict__ Wt) {
  const int wi = blockIdx.x >> 4;          // 0..2
  const int c0 = (blockIdx.x & 15) * 64;
  const float* W = (wi == 0) ? Wq : (wi == 1) ? Wk : Wv;
  __shared__ float ws[64][65];
  const int t = threadIdx.x;
  const int r = t >> 2;                    // c-row within chunk
  const int cb = (t & 3) * 16;             // h-col base
#pragma unroll
  for (int j = 0; j < 4; ++j) {
    const f32x4 v = *(const f32x4*)&W[(size_t)(c0 + r) * HS + cb + 4 * j];
    ws[cb + 4 * j + 0][r] = v[0];
    ws[cb + 4 * j + 1][r] = v[1];
    ws[cb + 4 * j + 2][r] = v[2];
    ws[cb + 4 * j + 3][r] = v[3];
  }
  __syncthreads();
  const int h = t >> 2;                    // output n-row within chunk
  const int rb = (t & 3) * 16;             // c base
  union { short8 s8[2]; unsigned short u[16]; } o;
#pragma unroll
  for (int i = 0; i < 16; ++i) o.u[i] = f2bf(ws[h][rb + i]);
  short8* dst = (short8*)(Wt + (size_t)(wi * 64 + h) * C + c0 + rb);
  dst[0] = o.s8[0];
  dst[1] = o.s8[1];
}

// ---------------------------------------------------------------------------
// Kernel 1: fused QKV projection GEMM, v4.
// 256 blocks (BM=64, 1 block/CU) x 8 waves (512 thr). BK=128, 8 K-steps,
// double-buffered LDS for BOTH operands (128 KB total):
//   B: 48 frags (192 cols x 128 k) staged via global_load_lds w=16,
//      frag-ordered linear layout [frag][lane*16B]  (conflict-free).
//   A: 64 rows x 128 k bf16, reg->cvt->ds_write_b128 with XOR swizzle
//      byte ^= (row&7)<<4 on write AND read (T2; read = 16 rows at same
//      k-range -> 2-way only instead of 16-way).
// Wave (wm,wn) = 32 rows x 48 cols -> acc[2][3], 24 MFMA per K-step.
// A x-loads issued one full iteration ahead; stage issued before compute.
// ---------------------------------------------------------------------------
__global__ __launch_bounds__(512, 2) void proj_kernel(
    const float* __restrict__ x, const unsigned short* __restrict__ Wt,
    const float* __restrict__ bq, const float* __restrict__ bk,
    const float* __restrict__ bv,
    unsigned short* __restrict__ Qb, unsigned short* __restrict__ Kb,
    unsigned short* __restrict__ Vt) {
  const int m0   = blockIdx.x * 64;
  const int w    = threadIdx.x >> 6;   // 0..7
  const int lane = threadIdx.x & 63;
  const int col  = lane & 15, grp = lane >> 4;
  const int wm   = w >> 2;             // 0..1: row half (32 rows)
  const int wn   = w & 3;              // 0..3: col group (48 cols)
  const int phase = blockIdx.x & 7;

  __shared__ unsigned short A_lds[2][64 * 128];   // 32 KB, XOR-swizzled rows
  __shared__ unsigned short B_lds[2][48][512];    // 96 KB, frag-ordered

  // A global: thread t loads row t>>3, 16 floats at kseg=(t&7)*16
  const int arow  = threadIdx.x >> 3;
  const int akoff = (threadIdx.x & 7) * 16;
  const float* xp = x + (size_t)(m0 + arow) * C + akoff;

  f32x4 acc[2][3];
#pragma unroll
  for (int mf = 0; mf < 2; ++mf)
#pragma unroll
    for (int jj = 0; jj < 3; ++jj) acc[mf][jj] = (f32x4){0.f, 0.f, 0.f, 0.f};

  auto kcOf = [&](int it) { return ((it + phase) & 7) * 128; };

  // stage this wave's 6 of the 48 B-fragments into B_lds[nb]
  auto stageB = [&](int nb, int kc) {
#pragma unroll
    for (int j = 0; j < 6; ++j) {
      const int f   = w * 6 + j;
      const int nt  = f % 12;
      const int k32 = f / 12;
      const unsigned short* src =
          Wt + (size_t)(nt * 16 + col) * C + kc + k32 * 32 + grp * 8;
      __builtin_amdgcn_global_load_lds(
          (const __attribute__((address_space(1))) void*)src,
          (__attribute__((address_space(3))) void*)&B_lds[nb][f][0],
          16, 0, 0);
    }
  };

  auto loadAreg = [&](int kc, f32x4 (&r)[4]) {
#pragma unroll
    for (int i = 0; i < 4; ++i) r[i] = *(const f32x4*)(xp + kc + 4 * i);
  };

  auto writeA = [&](int nb, const f32x4 (&r)[4]) {
    union { short8 s8[2]; unsigned short u[16]; } o;
#pragma unroll
    for (int i = 0; i < 4; ++i)
#pragma unroll
      for (int e = 0; e < 4; ++e) o.u[4 * i + e] = f2bf(r[i][e]);
    const int b0 = arow * 256 + (threadIdx.x & 7) * 32;   // byte offset
    const int s  = (arow & 7) << 4;                        // XOR swizzle
    char* base = (char*)&A_lds[nb][0];
    *(short8*)(base + ((b0     ) ^ s)) = o.s8[0];
    *(short8*)(base + ((b0 + 16) ^ s)) = o.s8[1];
  };

  auto readA = [&](int buf, int mf, int k32) {
    const int row = wm * 32 + mf * 16 + col;               // row&7 == col&7
    const int b = row * 256 + ((k32 * 64 + grp * 16) ^ ((col & 7) << 4));
    return *(const short8*)((const char*)&A_lds[buf][0] + b);
  };

  auto compute = [&](int buf) {
#pragma unroll
    for (int k32 = 0; k32 < 4; ++k32) {
      const short8 a0 = readA(buf, 0, k32);
      const short8 a1 = readA(buf, 1, k32);
#pragma unroll
      for (int jj = 0; jj < 3; ++jj) {
        const short8 bf =
            *(const short8*)&B_lds[buf][k32 * 12 + wn * 3 + jj][(size_t)lane * 8];
        acc[0][jj] = MFMA16(a0, bf, acc[0][jj]);
        acc[1][jj] = MFMA16(a1, bf, acc[1][jj]);
      }
    }
  };

  f32x4 arA[4];
  loadAreg(kcOf(0), arA);
  stageB(0, kcOf(0));
  writeA(0, arA);
  loadAreg(kcOf(1), arA);        // it=1's A, in flight across it=0
  __syncthreads();

  for (int it = 0; it < 8; ++it) {
    const int buf = it & 1;
    if (it < 7) stageB(buf ^ 1, kcOf(it + 1));   // B loads fly under compute
    compute(buf);
    if (it < 7) {
      writeA(buf ^ 1, arA);                      // cvt+write (loads landed)
      if (it < 6) loadAreg(kcOf(it + 2), arA);   // refill for next iter
    }
    __syncthreads();                             // drains vmcnt+lgkm for buf^1
  }

  auto writeOut = [&](int row, int n, float v) {
    if (n < 64)       Qb[(size_t)row * HS + n] = f2bf(v * 0.03125f);
    else if (n < 128) Kb[(size_t)row * HS + (n - 64)] = f2bf(v);
    else Vt[((size_t)(row >> 12) * HS + (n - 128)) * T + (row & (T - 1))] = f2bf(v);
  };
#pragma unroll
  for (int mf = 0; mf < 2; ++mf) {
#pragma unroll
    for (int jj = 0; jj < 3; ++jj) {
      const int n = wn * 48 + jj * 16 + col;
      const float bias = (n < 64) ? bq[n] : (n < 128) ? bk[n - 64] : bv[n - 128];
#pragma unroll
      for (int r = 0; r < 4; ++r)
        writeOut(m0 + wm * 32 + mf * 16 + 4 * grp + r, n, acc[mf][jj][r] + bias);
    }
  }
}

// ---------------------------------------------------------------------------
// Kernel 2: flash attention, 32x32 MFMA, fully swapped operands (unchanged).
// ---------------------------------------------------------------------------
__global__ __launch_bounds__(256, 2) void attn_kernel(
    const unsigned short* __restrict__ Qb,
    const unsigned short* __restrict__ Kb,
    const unsigned short* __restrict__ Vt,
    float* __restrict__ out) {
  const int lane = threadIdx.x & 63;
  const int w    = threadIdx.x >> 6;   // 0..3
  const int q    = lane & 31;
  const int hi   = lane >> 5;          // 0..1
  const int b    = blockIdx.x >> 7;    // 128 q-tiles per batch
  const int qt   = blockIdx.x & 127;
  const int qbase = qt * 32;
  const int qg    = qbase + q;

  __shared__ float accL[4][64][33];
  __shared__ float mL[4][32], lL[4][32], invL[32];

  const unsigned short* Qp  = Qb + (size_t)(b * T + qbase + q) * HS + 8 * hi;
  const unsigned short* Kbb = Kb + (size_t)b * T * HS;
  const unsigned short* Vtb = Vt + (size_t)b * HS * T;

  short8 qf[4];
#pragma unroll
  for (int j = 0; j < 4; ++j) qf[j] = *(const short8*)(Qp + 16 * j);

  f32x16 acc0, acc1;
#pragma unroll
  for (int r = 0; r < 16; ++r) { acc0[r] = 0.f; acc1[r] = 0.f; }
  float m = -INFINITY, lsum = 0.f;

  const int nkv = qt + 1;

  short8 kA[4], kB[4];

  auto loadK = [&](int k0, short8 (&kd)[4]) {
    const unsigned short* p = Kbb + (size_t)(k0 + q) * HS + 8 * hi;
    kd[0] = *(const short8*)(p);
    kd[1] = *(const short8*)(p + 16);
    kd[2] = *(const short8*)(p + 32);
    kd[3] = *(const short8*)(p + 48);
  };

  auto step = [&](int kb, short8 (&kc)[4], short8 (&kn)[4]) {
    const int k0 = kb * 32;
    const unsigned short* vp = Vtb + (size_t)q * T + k0 + 8 * hi;
    const short8 v00 = *(const short8*)(vp);
    const short8 v01 = *(const short8*)(vp + 16);
    const short8 v10 = *(const short8*)(vp + (size_t)32 * T);
    const short8 v11 = *(const short8*)(vp + (size_t)32 * T + 16);
    int knx = k0 + 128;
    if (knx > T - 32) knx = T - 32;
    loadK(knx, kn);

    f32x16 s;
#pragma unroll
    for (int r = 0; r < 16; ++r) s[r] = 0.f;
    s = MFMA32(kc[0], qf[0], s);
    s = MFMA32(kc[1], qf[1], s);
    s = MFMA32(kc[2], qf[2], s);
    s = MFMA32(kc[3], qf[3], s);

    const int qrel = qg - k0;
    float pe[16];
#pragma unroll
    for (int r = 0; r < 16; ++r) {
      const int key = (r & 3) + 8 * (r >> 2) + 4 * hi;
      pe[r] = (key <= qrel) ? s[r] : -INFINITY;
    }
    float t0 = fmaxf(fmaxf(pe[0], pe[1]), fmaxf(pe[2], pe[3]));
    float t1 = fmaxf(fmaxf(pe[4], pe[5]), fmaxf(pe[6], pe[7]));
    float t2 = fmaxf(fmaxf(pe[8], pe[9]), fmaxf(pe[10], pe[11]));
    float t3 = fmaxf(fmaxf(pe[12], pe[13]), fmaxf(pe[14], pe[15]));
    float pm = fmaxf(fmaxf(t0, t1), fmaxf(t2, t3));
    pm = fmaxf(pm, __shfl_xor(pm, 32, 64));

    const float mn = fmaxf(m, pm);
    if (!__all(mn == m)) {
      const float corr = __expf(m - mn);
      lsum *= corr;
#pragma unroll
      for (int r = 0; r < 16; ++r) { acc0[r] *= corr; acc1[r] *= corr; }
      m = mn;
    }
    float ps = 0.f;
#pragma unroll
    for (int r = 0; r < 16; ++r) {
      pe[r] = __expf(pe[r] - m);
      ps += pe[r];
    }
    ps += __shfl_xor(ps, 32, 64);
    lsum += ps;

    unsigned own[8], oth[8];
#pragma unroll
    for (int j = 0; j < 8; ++j) own[j] = pack_bf2(pe[2 * j], pe[2 * j + 1]);
#pragma unroll
    for (int j = 0; j < 8; ++j) oth[j] = __shfl_xor(own[j], 32, 64);
    union U { short8 s8; unsigned u[4]; };
    U p0, p1;
    p0.u[0] = hi ? oth[2] : own[0];
    p0.u[1] = hi ? oth[3] : own[1];
    p0.u[2] = hi ? own[2] : oth[0];
    p0.u[3] = hi ? own[3] : oth[1];
    p1.u[0] = hi ? oth[6] : own[4];
    p1.u[1] = hi ? oth[7] : own[5];
    p1.u[2] = hi ? own[6] : oth[4];
    p1.u[3] = hi ? own[7] : oth[5];

    acc0 = MFMA32(v00, p0.s8, acc0);
    acc0 = MFMA32(v01, p1.s8, acc0);
    acc1 = MFMA32(v10, p0.s8, acc1);
    acc1 = MFMA32(v11, p1.s8, acc1);
  };

  if (w < nkv) {
    loadK(32 * w, kA);
    int kb = w;
    while (true) {
      step(kb, kA, kB); kb += 4; if (kb >= nkv) break;
      step(kb, kB, kA); kb += 4; if (kb >= nkv) break;
    }
  }

  if (hi == 0) { mL[w][q] = m; lL[w][q] = lsum; }
  __syncthreads();
  {
    const float Mv = fmaxf(fmaxf(mL[0][q], mL[1][q]), fmaxf(mL[2][q], mL[3][q]));
    const float f = __expf(m - Mv);
#pragma unroll
    for (int r = 0; r < 16; ++r) {
      const int d = (r & 3) + 8 * (r >> 2) + 4 * hi;
      accL[w][d][q]      = acc0[r] * f;
      accL[w][d + 32][q] = acc1[r] * f;
    }
  }
  __syncthreads();
  if (threadIdx.x < 32) {
    const int qq = threadIdx.x;
    const float Mv = fmaxf(fmaxf(mL[0][qq], mL[1][qq]), fmaxf(mL[2][qq], mL[3][qq]));
    float L = 0.f;
#pragma unroll
    for (int ww = 0; ww < 4; ++ww) L += lL[ww][qq] * __expf(mL[ww][qq] - Mv);
    invL[qq] = 1.f / L;
  }
  __syncthreads();
#pragma unroll
  for (int p = 0; p < 8; ++p) {
    const int qq = (threadIdx.x >> 6) + 4 * p;
    const int d  = threadIdx.x & 63;
    const float v = accL[0][d][qq] + accL[1][d][qq] +
                    accL[2][d][qq] + accL[3][d][qq];
    out[(size_t)(b * T + qbase + qq) * HS + d] = v * invL[qq];
  }
}

extern "C" void kernel_launch(void* const* d_in, const int* in_sizes, int n_in,
                              void* d_out, int out_size, void* d_ws, size_t ws_size,
                              hipStream_t stream) {
  const float* x  = (const float*)d_in[0];
  const float* Wq = (const float*)d_in[1];
  const float* bq = (const float*)d_in[2];
  const float* Wk = (const float*)d_in[3];
  const float* bk = (const float*)d_in[4];
  const float* Wv = (const float*)d_in[5];
  const float* bv = (const float*)d_in[6];
  float* out = (float*)d_out;

  unsigned short* Qb = (unsigned short*)d_ws;
  unsigned short* Kb = Qb + (size_t)B * T * HS;
  unsigned short* Vt = Kb + (size_t)B * T * HS;
  unsigned short* Wt = Vt + (size_t)B * T * HS;

  conv_w_kernel<<<48, 256, 0, stream>>>(Wq, Wk, Wv, Wt);
  proj_kernel<<<B * T / 64, 512, 0, stream>>>(x, Wt, bq, bk, bv, Qb, Kb, Vt);
  attn_kernel<<<B * (T / 32), 256, 0, stream>>>(Qb, Kb, Vt, out);
}